// Round 7
// baseline (918.749 us; speedup 1.0000x reference)
//
#include <hip/hip_runtime.h>
#include <math.h>

#define T_     4096
#define BH_    64
#define EPS_   1e-6f
#define SCALE_ 0.0625f   // 1/sqrt(256)

typedef _Float16 h16;
typedef __attribute__((ext_vector_type(2))) _Float16 h16x2;
typedef __attribute__((ext_vector_type(4))) _Float16 h16x4;
typedef __attribute__((ext_vector_type(8))) _Float16 h16x8;
typedef __attribute__((ext_vector_type(2))) __fp16   fp16x2r;   // raw builtin return type
typedef __attribute__((ext_vector_type(4))) short    short4v;
typedef __attribute__((ext_vector_type(8))) short    bf16x8;
typedef __attribute__((ext_vector_type(4))) float    f32x4;
typedef __attribute__((ext_vector_type(4))) unsigned uint4v;

__device__ __forceinline__ h16x2 pkrtz(float a, float b) {
    fp16x2r r = __builtin_amdgcn_cvt_pkrtz(a, b);
    h16x2 o; o.x = (h16)r.x; o.y = (h16)r.y;
    return o;
}

__device__ __forceinline__ void bfsplit(float x, short& h, short& l) {
    unsigned u = __float_as_uint(x) + 0x8000u;       // round-half-up to bf16
    unsigned hb = u & 0xffff0000u;
    h = (short)(u >> 16);
    float lf = x - __uint_as_float(hb);              // exact residual
    l = (short)(__float_as_uint(lf) >> 16);          // truncated residual
}
// pack bf16(a) (low) | bf16(b) (high), round-half-up; returns residual bit patterns
__device__ __forceinline__ unsigned pk_hi2(float a, float b, unsigned& ra, unsigned& rb) {
    unsigned ua = __float_as_uint(a) + 0x8000u;
    unsigned ub = __float_as_uint(b) + 0x8000u;
    ra = ua & 0xffff0000u; rb = ub & 0xffff0000u;
    return __builtin_amdgcn_perm(ub, ua, 0x07060302u);
}
__device__ __forceinline__ unsigned pk_tr2(float a, float b) {   // truncating pack
    return __builtin_amdgcn_perm(__float_as_uint(b), __float_as_uint(a), 0x07060302u);
}
__device__ __forceinline__ bf16x8 mkbf8(unsigned a, unsigned b, unsigned c, unsigned d) {
    uint4v t; t.x = a; t.y = b; t.z = c; t.w = d;
    return __builtin_bit_cast(bf16x8, t);
}

// ============================================================
// prep: W (64x256) -> (a) W^T padded f16 hi/lo planes [256][72] (stage1)
//                     (b) MFMA-frag-ordered planes wfg (stage2):
//       frag(r,w,q)[8] = W^T[r][w*32+q*4..+3] ++ W^T[r][w*32+16+q*4..+3]
// ============================================================
__global__ __launch_bounds__(256)
void k_prep(const float* __restrict__ Wg, h16* __restrict__ wtp, h16* __restrict__ wfg)
{
    int d = blockIdx.x;      // 0..63
    int r = threadIdx.x;     // 0..255
    float x = Wg[d * 256 + r];
    h16 hi = (h16)x;
    h16 lo = (h16)(x - (float)hi);
    wtp[r * 72 + d]            = hi;
    wtp[256 * 72 + r * 72 + d] = lo;
    int w = d >> 5, rem = d & 31;
    int half = rem >> 4, qq = (rem >> 2) & 3, i = rem & 3;
    int dst = (r * 8 + w * 4 + qq) * 8 + half * 4 + i;
    wfg[dst]         = hi;
    wfg[16384 + dst] = lo;
}

// ============================================================
// Stage 1: UNCHANGED from round 6 (byte-identical) for attribution.
// ============================================================
__global__ __launch_bounds__(512, 2)
void k_stage1(const float* __restrict__ kg, const float* __restrict__ vg,
              const float* __restrict__ mg, const h16* __restrict__ wtp,
              float* __restrict__ kv_part, float* __restrict__ ks_part, int nch)
{
    __shared__ __align__(16) char smem[148480];
    h16*   Wt   = (h16*)smem;                       // [2][256*72]   73728 B
    h16*   kT0  = (h16*)(smem + 73728);             // [128*72]      18432 B
    h16*   kT1  = (h16*)(smem + 92160);             // [128*72]      18432 B
    short* vTh  = (short*)(smem + 110592);          // [64*136]      17408 B
    short* vTl  = (short*)(smem + 128000);          // [64*136]      17408 B
    float* np2  = (float*)(smem + 145408);          // [128]           512 B
    float* mskl = (float*)(smem + 145920);          // [128]           512 B
    float* ksb  = (float*)(smem + 146432);          // [2][256]       2048 B
    float* red  = (float*)(smem + 73728);           // alias kT/vT: 256*68*4 = 69632 B

    const int tid  = threadIdx.x;
    const int lane = tid & 63, l15 = lane & 15, q = lane >> 4;
    const int wid  = tid >> 6;
    const int rg = wid & 3, tg = wid >> 2;
    const int s = blockIdx.x, bh = blockIdx.y, b = bh >> 4;
    const long rowb = (long)bh * T_;
    const int tcb = s * (nch * 128);

    {   // stage W^T hi/lo
        const float4* src = (const float4*)wtp;
        float4* dst = (float4*)Wt;
#pragma unroll
        for (int i = 0; i < 9; ++i) dst[i * 512 + tid] = src[i * 512 + tid];
    }

    f32x4 kva[4][4];
#pragma unroll
    for (int a = 0; a < 4; ++a)
#pragma unroll
        for (int c2 = 0; c2 < 4; ++c2) { f32x4 z4 = {0.f,0.f,0.f,0.f}; kva[a][c2] = z4; }
    float ksa[4] = {0.f, 0.f, 0.f, 0.f};

    const int tRow = tid >> 4;          // 0..31
    const int c4   = (tid & 15) * 4;

    for (int c = 0; c < nch; ++c) {
        const long tcc = tcb + (long)c * 128;
        __syncthreads();   // prev chunk fully consumed; Wt staged (c==0)

#pragma unroll
        for (int p = 0; p < 4; ++p) {
            int t = p * 32 + tRow;
            float4 xk = *(const float4*)&kg[(rowb + tcc + t) * 64 + c4];
            float4 xv = *(const float4*)&vg[(rowb + tcc + t) * 64 + c4];
            float  mk = mg[b * T_ + tcc + t];

            float s2 = xk.x*xk.x + xk.y*xk.y + xk.z*xk.z + xk.w*xk.w;
            s2 += __shfl_xor(s2, 1); s2 += __shfl_xor(s2, 2);
            s2 += __shfl_xor(s2, 4); s2 += __shfl_xor(s2, 8);
            h16x2 h01 = pkrtz(xk.x, xk.y);
            h16x2 h23 = pkrtz(xk.z, xk.w);
            h16x2 l01 = pkrtz(xk.x - (float)h01.x, xk.y - (float)h01.y);
            h16x2 l23 = pkrtz(xk.z - (float)h23.x, xk.w - (float)h23.y);
            h16x4 hv, lv;
            hv.x = h01.x; hv.y = h01.y; hv.z = h23.x; hv.w = h23.y;
            lv.x = l01.x; lv.y = l01.y; lv.z = l23.x; lv.w = l23.y;
            *(h16x4*)&kT0[t * 72 + c4] = hv;
            *(h16x4*)&kT1[t * 72 + c4] = lv;
            if ((tid & 15) == 0) { np2[t] = 0.5f * s2; mskl[t] = mk * SCALE_; }

            xv.x *= mk; xv.y *= mk; xv.z *= mk; xv.w *= mk;
            short h, l;
            bfsplit(xv.x, h, l); vTh[(c4+0)*136 + t] = h; vTl[(c4+0)*136 + t] = l;
            bfsplit(xv.y, h, l); vTh[(c4+1)*136 + t] = h; vTl[(c4+1)*136 + t] = l;
            bfsplit(xv.z, h, l); vTh[(c4+2)*136 + t] = h; vTl[(c4+2)*136 + t] = l;
            bfsplit(xv.w, h, l); vTh[(c4+3)*136 + t] = h; vTl[(c4+3)*136 + t] = l;
        }
        __syncthreads();

        f32x4 pr[4][4];
#pragma unroll
        for (int m = 0; m < 4; ++m)
#pragma unroll
            for (int n = 0; n < 4; ++n) { f32x4 z4 = {0.f,0.f,0.f,0.f}; pr[m][n] = z4; }

#pragma unroll
        for (int w = 0; w < 2; ++w) {
            h16x8 wbh[4], wbl[4];
#pragma unroll
            for (int n = 0; n < 4; ++n) {
                int base = (rg * 64 + n * 16 + l15) * 72 + w * 32 + q * 4;
                h16x4 a0 = *(const h16x4*)&Wt[base];
                h16x4 a1 = *(const h16x4*)&Wt[base + 16];
                h16x4 b0 = *(const h16x4*)&Wt[256 * 72 + base];
                h16x4 b1 = *(const h16x4*)&Wt[256 * 72 + base + 16];
                h16x8 hv, lv;
                hv[0]=a0.x; hv[1]=a0.y; hv[2]=a0.z; hv[3]=a0.w; hv[4]=a1.x; hv[5]=a1.y; hv[6]=a1.z; hv[7]=a1.w;
                lv[0]=b0.x; lv[1]=b0.y; lv[2]=b0.z; lv[3]=b0.w; lv[4]=b1.x; lv[5]=b1.y; lv[6]=b1.z; lv[7]=b1.w;
                wbh[n] = hv; wbl[n] = lv;
            }
#pragma unroll
            for (int m = 0; m < 4; ++m) {
                int base = (tg * 64 + m * 16 + l15) * 72 + w * 32 + q * 4;
                h16x4 a0 = *(const h16x4*)&kT0[base];
                h16x4 a1 = *(const h16x4*)&kT0[base + 16];
                h16x4 b0 = *(const h16x4*)&kT1[base];
                h16x4 b1 = *(const h16x4*)&kT1[base + 16];
                h16x8 Ah, Al;
                Ah[0]=a0.x; Ah[1]=a0.y; Ah[2]=a0.z; Ah[3]=a0.w; Ah[4]=a1.x; Ah[5]=a1.y; Ah[6]=a1.z; Ah[7]=a1.w;
                Al[0]=b0.x; Al[1]=b0.y; Al[2]=b0.z; Al[3]=b0.w; Al[4]=b1.x; Al[5]=b1.y; Al[6]=b1.z; Al[7]=b1.w;
#pragma unroll
                for (int n = 0; n < 4; ++n) {
                    pr[m][n] = __builtin_amdgcn_mfma_f32_16x16x32_f16(Ah, wbh[n], pr[m][n], 0, 0, 0);
                    pr[m][n] = __builtin_amdgcn_mfma_f32_16x16x32_f16(Ah, wbl[n], pr[m][n], 0, 0, 0);
                    pr[m][n] = __builtin_amdgcn_mfma_f32_16x16x32_f16(Al, wbh[n], pr[m][n], 0, 0, 0);
                }
            }
        }

#pragma unroll
        for (int W = 0; W < 2; ++W) {
            const int m0 = 2 * W, m1 = 2 * W + 1;
            const int rb0 = tg * 64 + m0 * 16 + q * 4;
            float4 nq0 = *(const float4*)&np2[rb0];
            float4 nq1 = *(const float4*)&np2[rb0 + 16];
            float4 sm0 = *(const float4*)&mskl[rb0];
            float4 sm1 = *(const float4*)&mskl[rb0 + 16];
            bf16x8 aph[4], apl[4];
#pragma unroll
            for (int n = 0; n < 4; ++n) {
                float e0[4], e1[4];
                e0[0] = __expf(pr[m0][n][0] - nq0.x) * sm0.x;
                e0[1] = __expf(pr[m0][n][1] - nq0.y) * sm0.y;
                e0[2] = __expf(pr[m0][n][2] - nq0.z) * sm0.z;
                e0[3] = __expf(pr[m0][n][3] - nq0.w) * sm0.w;
                e1[0] = __expf(pr[m1][n][0] - nq1.x) * sm1.x;
                e1[1] = __expf(pr[m1][n][1] - nq1.y) * sm1.y;
                e1[2] = __expf(pr[m1][n][2] - nq1.z) * sm1.z;
                e1[3] = __expf(pr[m1][n][3] - nq1.w) * sm1.w;
                ksa[n] += e0[0]+e0[1]+e0[2]+e0[3]+e1[0]+e1[1]+e1[2]+e1[3];
                unsigned r0,r1,r2,r3,r4,r5,r6,r7;
                unsigned h01 = pk_hi2(e0[0], e0[1], r0, r1);
                unsigned h23 = pk_hi2(e0[2], e0[3], r2, r3);
                unsigned h45 = pk_hi2(e1[0], e1[1], r4, r5);
                unsigned h67 = pk_hi2(e1[2], e1[3], r6, r7);
                unsigned l01 = pk_tr2(e0[0]-__uint_as_float(r0), e0[1]-__uint_as_float(r1));
                unsigned l23 = pk_tr2(e0[2]-__uint_as_float(r2), e0[3]-__uint_as_float(r3));
                unsigned l45 = pk_tr2(e1[0]-__uint_as_float(r4), e1[1]-__uint_as_float(r5));
                unsigned l67 = pk_tr2(e1[2]-__uint_as_float(r6), e1[3]-__uint_as_float(r7));
                aph[n] = mkbf8(h01, h23, h45, h67);
                apl[n] = mkbf8(l01, l23, l45, l67);
            }
            bf16x8 bvh[4], bvl[4];
#pragma unroll
            for (int nd = 0; nd < 4; ++nd) {
                int base = (nd * 16 + l15) * 136 + tg * 64 + W * 32 + q * 4;
                short4v a0 = *(const short4v*)&vTh[base];
                short4v a1 = *(const short4v*)&vTh[base + 16];
                short4v b0 = *(const short4v*)&vTl[base];
                short4v b1 = *(const short4v*)&vTl[base + 16];
                bf16x8 hv, lv;
                hv[0]=a0.x; hv[1]=a0.y; hv[2]=a0.z; hv[3]=a0.w; hv[4]=a1.x; hv[5]=a1.y; hv[6]=a1.z; hv[7]=a1.w;
                lv[0]=b0.x; lv[1]=b0.y; lv[2]=b0.z; lv[3]=b0.w; lv[4]=b1.x; lv[5]=b1.y; lv[6]=b1.z; lv[7]=b1.w;
                bvh[nd] = hv; bvl[nd] = lv;
            }
#pragma unroll
            for (int n = 0; n < 4; ++n)
#pragma unroll
                for (int nd = 0; nd < 4; ++nd) {
                    kva[n][nd] = __builtin_amdgcn_mfma_f32_16x16x32_bf16(aph[n], bvh[nd], kva[n][nd], 0, 0, 0);
                    kva[n][nd] = __builtin_amdgcn_mfma_f32_16x16x32_bf16(aph[n], bvl[nd], kva[n][nd], 0, 0, 0);
                    kva[n][nd] = __builtin_amdgcn_mfma_f32_16x16x32_bf16(apl[n], bvh[nd], kva[n][nd], 0, 0, 0);
                }
        }
    }

    __syncthreads();
#pragma unroll
    for (int n = 0; n < 4; ++n) {
        float v = ksa[n];
        v += __shfl_xor(v, 16);
        v += __shfl_xor(v, 32);
        if (q == 0) ksb[tg * 256 + rg * 64 + n * 16 + l15] = v;
    }
    if (tg == 0) {
#pragma unroll
        for (int n = 0; n < 4; ++n)
#pragma unroll
            for (int nd = 0; nd < 4; ++nd)
#pragma unroll
                for (int j = 0; j < 4; ++j)
                    red[(rg * 64 + n * 16 + q * 4 + j) * 68 + nd * 16 + l15] = kva[n][nd][j];
    }
    __syncthreads();
    if (tg == 1) {
#pragma unroll
        for (int n = 0; n < 4; ++n)
#pragma unroll
            for (int nd = 0; nd < 4; ++nd)
#pragma unroll
                for (int j = 0; j < 4; ++j)
                    red[(rg * 64 + n * 16 + q * 4 + j) * 68 + nd * 16 + l15] += kva[n][nd][j];
    }
    __syncthreads();
    {
        float* dst = kv_part + (long)(s * BH_ + bh) * (256 * 64);
#pragma unroll
        for (int i = 0; i < 8; ++i) {
            int flat = (i * 512 + tid) * 4;
            int r = flat >> 6, d = flat & 63;
            *(float4*)(dst + flat) = *(const float4*)&red[r * 68 + d];
        }
        if (tid < 256) ks_part[(long)(s * BH_ + bh) * 256 + tid] = ksb[tid] + ksb[256 + tid];
    }
}

// ============================================================
// Reduce: UNCHANGED from round 6.
// ============================================================
__global__ __launch_bounds__(256)
void k_reduce(const float* __restrict__ kvp, const float* __restrict__ ksp,
              short* __restrict__ kvt, float* __restrict__ ksf, int split)
{
    __shared__ __align__(16) float red2[32 * 68];
    const int tid = threadIdx.x, rq = blockIdx.x, bh = blockIdx.y;
    const long NKV4 = (long)BH_ * 256 * 64 / 4;
#pragma unroll
    for (int i = 0; i < 2; ++i) {
        int idx4 = i * 256 + tid;
        long g = (long)bh * 4096 + rq * 512 + idx4;
        float4 a = ((const float4*)kvp)[g];
        for (int p = 1; p < split; ++p) {
            float4 t = ((const float4*)kvp)[(long)p * NKV4 + g];
            a.x += t.x; a.y += t.y; a.z += t.z; a.w += t.w;
        }
        int flat = idx4 * 4;
        int rl = flat >> 6, d = flat & 63;
        *(float4*)&red2[rl * 68 + d] = a;
    }
    if (tid < 32) {
        float s = 0.f;
        for (int p = 0; p < split; ++p) s += ksp[(long)p * (BH_ * 256) + bh * 256 + rq * 32 + tid];
        ksf[bh * 256 + rq * 32 + tid] = s;
    }
    __syncthreads();
    short* dh = kvt + (long)bh * 33792;
    short* dl = dh + 16896;
#pragma unroll
    for (int i = 0; i < 8; ++i) {
        int flat = i * 256 + tid;
        int d = flat >> 5, rl = flat & 31;
        short h, l;
        bfsplit(red2[rl * 68 + d], h, l);
        dh[d * 264 + rq * 32 + rl] = h;
        dl[d * 264 + rq * 32 + rl] = l;
    }
}

// ============================================================
// Stage 2: zero-barrier t-wave split, r-quarters. W from GLOBAL frag
// layout (L2-hot) -> LDS = kvt + ksum only (68.6 KB) -> 2 blocks/CU,
// 4 waves/SIMD (launch_bounds(512,4)). grid(8, BH), 4 tiles/block.
// ============================================================
__global__ __launch_bounds__(512, 4)
void k_stage2(const float* __restrict__ qg, const h16* __restrict__ wfg,
              const short* __restrict__ kvt, const float* __restrict__ ksf,
              float* __restrict__ outg)
{
    __shared__ __align__(16) char smem[68608];
    short* kvTh   = (short*)smem;                   // [64*264] 33792 B
    short* kvTl   = (short*)(smem + 33792);         // [64*264] 33792 B
    float* ksum_l = (float*)(smem + 67584);         // [256]     1024 B

    const int tid  = threadIdx.x;
    const int lane = tid & 63, l15 = lane & 15, q = lane >> 4;
    const int wid  = tid >> 6;
    const int bh = blockIdx.y, qd = blockIdx.x;
    const long rowb = (long)bh * T_;

    {
        const float4* s2p = (const float4*)(kvt + (long)bh * 33792);
        float4* d2 = (float4*)kvTh;
#pragma unroll
        for (int i = 0; i < 9; ++i) { int idx = i * 512 + tid; if (idx < 4224) d2[idx] = s2p[idx]; }
        if (tid < 256) ksum_l[tid] = ksf[bh * 256 + tid];
    }
    __syncthreads();

    const int trl = wid * 16 + l15;   // wave-local t row

    for (int it = 0; it < 4; ++it) {
        const int t0 = (qd * 4 + it) * 128;

        const float* qrow = &qg[(rowb + t0 + trl) * 64 + q * 4];
        float4 qr0 = *(const float4*)(qrow);
        float4 qr1 = *(const float4*)(qrow + 16);
        float4 qr2 = *(const float4*)(qrow + 32);
        float4 qr3 = *(const float4*)(qrow + 48);

        float s2 = qr0.x*qr0.x + qr0.y*qr0.y + qr0.z*qr0.z + qr0.w*qr0.w
                 + qr1.x*qr1.x + qr1.y*qr1.y + qr1.z*qr1.z + qr1.w*qr1.w
                 + qr2.x*qr2.x + qr2.y*qr2.y + qr2.z*qr2.z + qr2.w*qr2.w
                 + qr3.x*qr3.x + qr3.y*qr3.y + qr3.z*qr3.z + qr3.w*qr3.w;
        s2 += __shfl_xor(s2, 16);
        s2 += __shfl_xor(s2, 32);
        const float nrm = 0.5f * s2;

        h16x8 qbh[2], qbl[2];
#pragma unroll
        for (int w = 0; w < 2; ++w) {
            float4 a = (w == 0) ? qr0 : qr2;
            float4 b2 = (w == 0) ? qr1 : qr3;
            h16x2 h0 = pkrtz(a.x, a.y);
            h16x2 h1 = pkrtz(a.z, a.w);
            h16x2 h2 = pkrtz(b2.x, b2.y);
            h16x2 h3 = pkrtz(b2.z, b2.w);
            h16x2 l0 = pkrtz(a.x - (float)h0.x, a.y - (float)h0.y);
            h16x2 l1 = pkrtz(a.z - (float)h1.x, a.w - (float)h1.y);
            h16x2 l2 = pkrtz(b2.x - (float)h2.x, b2.y - (float)h2.y);
            h16x2 l3 = pkrtz(b2.z - (float)h3.x, b2.w - (float)h3.y);
            h16x8 hv, lv;
            hv[0]=h0.x; hv[1]=h0.y; hv[2]=h1.x; hv[3]=h1.y; hv[4]=h2.x; hv[5]=h2.y; hv[6]=h3.x; hv[7]=h3.y;
            lv[0]=l0.x; lv[1]=l0.y; lv[2]=l1.x; lv[3]=l1.y; lv[4]=l2.x; lv[5]=l2.y; lv[6]=l3.x; lv[7]=l3.y;
            qbh[w] = hv; qbl[w] = lv;
        }

        f32x4 oac[4];
#pragma unroll
        for (int nd = 0; nd < 4; ++nd) { f32x4 z4 = {0.f,0.f,0.f,0.f}; oac[nd] = z4; }
        float z = 0.f;

#pragma unroll
        for (int rq = 0; rq < 4; ++rq) {
            f32x4 pr[4];
#pragma unroll
            for (int mm = 0; mm < 4; ++mm) { f32x4 z4 = {0.f,0.f,0.f,0.f}; pr[mm] = z4; }
#pragma unroll
            for (int w = 0; w < 2; ++w) {
#pragma unroll
                for (int mm = 0; mm < 4; ++mm) {
                    int fb = (((rq * 4 + mm) * 16 + l15) * 8 + w * 4 + q) * 8;
                    h16x8 Ah = *(const h16x8*)&wfg[fb];
                    h16x8 Al = *(const h16x8*)&wfg[16384 + fb];
                    pr[mm] = __builtin_amdgcn_mfma_f32_16x16x32_f16(Ah, qbh[w], pr[mm], 0, 0, 0);
                    pr[mm] = __builtin_amdgcn_mfma_f32_16x16x32_f16(Ah, qbl[w], pr[mm], 0, 0, 0);
                    pr[mm] = __builtin_amdgcn_mfma_f32_16x16x32_f16(Al, qbh[w], pr[mm], 0, 0, 0);
                }
            }
#pragma unroll
            for (int Wl = 0; Wl < 2; ++Wl) {
                const int Wg2 = rq * 2 + Wl;
                const int m0 = 2 * Wl, m1 = 2 * Wl + 1;
                float4 ka = *(const float4*)&ksum_l[Wg2 * 32 + q * 4];
                float4 kb = *(const float4*)&ksum_l[Wg2 * 32 + 16 + q * 4];
                float e0[4], e1[4];
                e0[0] = __expf(pr[m0][0] - nrm) * SCALE_;
                e0[1] = __expf(pr[m0][1] - nrm) * SCALE_;
                e0[2] = __expf(pr[m0][2] - nrm) * SCALE_;
                e0[3] = __expf(pr[m0][3] - nrm) * SCALE_;
                e1[0] = __expf(pr[m1][0] - nrm) * SCALE_;
                e1[1] = __expf(pr[m1][1] - nrm) * SCALE_;
                e1[2] = __expf(pr[m1][2] - nrm) * SCALE_;
                e1[3] = __expf(pr[m1][3] - nrm) * SCALE_;
                z += e0[0]*ka.x + e0[1]*ka.y + e0[2]*ka.z + e0[3]*ka.w
                   + e1[0]*kb.x + e1[1]*kb.y + e1[2]*kb.z + e1[3]*kb.w;
                unsigned r0,r1,r2,r3,r4,r5,r6,r7;
                unsigned h01 = pk_hi2(e0[0], e0[1], r0, r1);
                unsigned h23 = pk_hi2(e0[2], e0[3], r2, r3);
                unsigned h45 = pk_hi2(e1[0], e1[1], r4, r5);
                unsigned h67 = pk_hi2(e1[2], e1[3], r6, r7);
                unsigned l01 = pk_tr2(e0[0]-__uint_as_float(r0), e0[1]-__uint_as_float(r1));
                unsigned l23 = pk_tr2(e0[2]-__uint_as_float(r2), e0[3]-__uint_as_float(r3));
                unsigned l45 = pk_tr2(e1[0]-__uint_as_float(r4), e1[1]-__uint_as_float(r5));
                unsigned l67 = pk_tr2(e1[2]-__uint_as_float(r6), e1[3]-__uint_as_float(r7));
                bf16x8 afh = mkbf8(h01, h23, h45, h67);
                bf16x8 afl = mkbf8(l01, l23, l45, l67);
#pragma unroll
                for (int nd = 0; nd < 4; ++nd) {
                    int base = (nd * 16 + l15) * 264 + Wg2 * 32 + q * 4;
                    short4v a0 = *(const short4v*)&kvTh[base];
                    short4v a1 = *(const short4v*)&kvTh[base + 16];
                    short4v b0 = *(const short4v*)&kvTl[base];
                    short4v b1 = *(const short4v*)&kvTl[base + 16];
                    bf16x8 hv, lv;
                    hv[0]=a0.x; hv[1]=a0.y; hv[2]=a0.z; hv[3]=a0.w; hv[4]=a1.x; hv[5]=a1.y; hv[6]=a1.z; hv[7]=a1.w;
                    lv[0]=b0.x; lv[1]=b0.y; lv[2]=b0.z; lv[3]=b0.w; lv[4]=b1.x; lv[5]=b1.y; lv[6]=b1.z; lv[7]=b1.w;
                    oac[nd] = __builtin_amdgcn_mfma_f32_16x16x32_bf16(afh, hv, oac[nd], 0, 0, 0);
                    oac[nd] = __builtin_amdgcn_mfma_f32_16x16x32_bf16(afh, lv, oac[nd], 0, 0, 0);
                    oac[nd] = __builtin_amdgcn_mfma_f32_16x16x32_bf16(afl, hv, oac[nd], 0, 0, 0);
                }
            }
        }

        z += __shfl_xor(z, 16);
        z += __shfl_xor(z, 32);
        float rz[4];
#pragma unroll
        for (int j = 0; j < 4; ++j) {
            float zj = __shfl(z, q * 4 + j);
            rz[j] = 1.f / (zj + EPS_);
        }
#pragma unroll
        for (int j = 0; j < 4; ++j) {
            long ro = (rowb + t0 + wid * 16 + 4 * q + j) * 64 + l15;
            outg[ro]      = oac[0][j] * rz[j];
            outg[ro + 16] = oac[1][j] * rz[j];
            outg[ro + 32] = oac[2][j] * rz[j];
            outg[ro + 48] = oac[3][j] * rz[j];
        }
    }
}

// ============================================================
extern "C" void kernel_launch(void* const* d_in, const int* in_sizes, int n_in,
                              void* d_out, int out_size, void* d_ws, size_t ws_size,
                              hipStream_t stream)
{
    const float* q  = (const float*)d_in[0];
    const float* k  = (const float*)d_in[1];
    const float* v  = (const float*)d_in[2];
    const float* m  = (const float*)d_in[3];
    const float* W  = (const float*)d_in[4];
    float* out = (float*)d_out;

    char* ws = (char*)d_ws;
    h16*   wtp = (h16*)ws;                                   // 73728 B
    h16*   wfg = (h16*)(ws + 73728);                         // 65536 B
    short* kvt = (short*)(ws + 73728 + 65536);               // 4325376 B
    float* ksf = (float*)(ws + 73728 + 65536 + 4325376);     // 65536 B

    int split = 4;
    while (split > 1) {
        size_t need = 73728ull + 65536ull + 4325376ull + 65536ull
                    + (size_t)split * (4194304ull + 65536ull);
        if (need <= ws_size) break;
        split >>= 1;
    }
    float* kvp = (float*)(ws + 73728 + 65536 + 4325376 + 65536);
    float* ksp = kvp + (size_t)split * (256 * 64 * BH_);
    int nch = (T_ / split) / 128;

    k_prep  <<<dim3(64),         dim3(256), 0, stream>>>(W, wtp, wfg);
    k_stage1<<<dim3(split, BH_), dim3(512), 0, stream>>>(k, v, m, wtp, kvp, ksp, nch);
    k_reduce<<<dim3(8, BH_),     dim3(256), 0, stream>>>(kvp, ksp, kvt, ksf, split);
    k_stage2<<<dim3(8, BH_),     dim3(512), 0, stream>>>(q, wfg, kvt, ksf, out);
}

// Round 8
// 327.432 us; speedup vs baseline: 2.8059x; 2.8059x over previous
//
#include <hip/hip_runtime.h>
#include <math.h>

#define T_     4096
#define BH_    64
#define EPS_   1e-6f
#define SCALE_ 0.0625f   // 1/sqrt(256)

typedef _Float16 h16;
typedef __attribute__((ext_vector_type(4))) _Float16 h16x4;
typedef __attribute__((ext_vector_type(8))) _Float16 h16x8;
typedef __attribute__((ext_vector_type(4))) short    short4v;
typedef __attribute__((ext_vector_type(8))) short    bf16x8;
typedef __attribute__((ext_vector_type(4))) float    f32x4;
typedef __attribute__((ext_vector_type(4))) unsigned uint4v;

__device__ __forceinline__ void bfsplit(float x, short& h, short& l) {
    unsigned u = __float_as_uint(x) + 0x8000u;       // round-half-up to bf16
    unsigned hb = u & 0xffff0000u;
    h = (short)(u >> 16);
    float lf = x - __uint_as_float(hb);              // exact residual
    l = (short)(__float_as_uint(lf) >> 16);          // truncated residual
}
// pack bf16(a) (low) | bf16(b) (high), round-half-up; returns residual bit patterns
__device__ __forceinline__ unsigned pk_hi2(float a, float b, unsigned& ra, unsigned& rb) {
    unsigned ua = __float_as_uint(a) + 0x8000u;
    unsigned ub = __float_as_uint(b) + 0x8000u;
    ra = ua & 0xffff0000u; rb = ub & 0xffff0000u;
    return __builtin_amdgcn_perm(ub, ua, 0x07060302u);
}
__device__ __forceinline__ unsigned pk_tr2(float a, float b) {   // truncating pack
    return __builtin_amdgcn_perm(__float_as_uint(b), __float_as_uint(a), 0x07060302u);
}
__device__ __forceinline__ bf16x8 mkbf8(unsigned a, unsigned b, unsigned c, unsigned d) {
    uint4v t; t.x = a; t.y = b; t.z = c; t.w = d;
    return __builtin_bit_cast(bf16x8, t);
}

// ============================================================
// prep: W (64x256) -> W^T padded f16 hi/lo planes [256][72]
// ============================================================
__global__ __launch_bounds__(256)
void k_prep(const float* __restrict__ Wg, h16* __restrict__ wtp)
{
    int d = blockIdx.x;      // 0..63
    int r = threadIdx.x;     // 0..255
    float x = Wg[d * 256 + r];
    h16 hi = (h16)x;
    h16 lo = (h16)(x - (float)hi);
    wtp[r * 72 + d]            = hi;
    wtp[256 * 72 + r * 72 + d] = lo;
}

// ============================================================
// Stage 1 (round-2 structure, OOB fixed): per (t-chunk s, head bh):
// stage v^T + k norms -> proj_k (f16x3, k from global) -> exp ->
// kv accumulate (bf16x3). 8 waves: (tg 0..1) x (rg 0..3).
// red[256x68] aliases the dead Wt region at block end.
// ============================================================
__global__ __launch_bounds__(512, 2)
void k_stage1(const float* __restrict__ kg, const float* __restrict__ vg,
              const float* __restrict__ mg, const h16* __restrict__ wtp,
              float* __restrict__ kv_part, float* __restrict__ ks_part, int nch)
{
    __shared__ __align__(16) char smem[113664];
    h16*   Wt     = (h16*)smem;                     // [2][256*72] 73728 B
    short* vTh    = (short*)(smem + 73728);         // [64*136]    17408 B
    short* vTl    = (short*)(smem + 91136);         // [64*136]    17408 B
    float* norm_l = (float*)(smem + 108544);        // [128]         512 B
    float* msk_l  = (float*)(smem + 109056);        // [128]         512 B
    float* np     = (float*)(smem + 109568);        // [4][128]     2048 B
    float* ksb    = (float*)(smem + 111616);        // [2][256]     2048 B
    float* red    = (float*)smem;                   // alias Wt: 256*68*4 = 69632 B

    const int tid  = threadIdx.x;
    const int lane = tid & 63, l15 = lane & 15, q = lane >> 4;
    const int wid  = tid >> 6;
    const int rg = wid & 3, tg = wid >> 2;
    const int s = blockIdx.x, bh = blockIdx.y, b = bh >> 4;
    const long rowb = (long)bh * T_;

    {   // stage W^T hi/lo
        const float4* src = (const float4*)wtp;
        float4* dst = (float4*)Wt;
#pragma unroll
        for (int i = 0; i < 9; ++i) dst[i * 512 + tid] = src[i * 512 + tid];
    }

    f32x4 kva[4][4];
#pragma unroll
    for (int a = 0; a < 4; ++a)
#pragma unroll
        for (int c2 = 0; c2 < 4; ++c2) { f32x4 z4 = {0.f,0.f,0.f,0.f}; kva[a][c2] = z4; }
    float ksa[4] = {0.f, 0.f, 0.f, 0.f};

    for (int c = 0; c < nch; ++c) {
        const int t0 = (s * nch + c) * 128;
        __syncthreads();   // prev chunk fully consumed; Wt staged (c==0)

        // ---- stage v^T (mask-scaled, bf16 hi/lo) + k row-norm partials ----
        {
            const int tlv = tid & 127, dq = tid >> 7;
            const float mval = mg[b * T_ + t0 + tlv];
            const float* vrow = vg + (rowb + t0 + tlv) * 64 + dq * 16;
            const float* krow = kg + (rowb + t0 + tlv) * 64 + dq * 16;
            float s2 = 0.f;
#pragma unroll
            for (int j = 0; j < 4; ++j) {
                float4 vv = *(const float4*)(vrow + j * 4);
                float4 kk = *(const float4*)(krow + j * 4);
                s2 += kk.x * kk.x + kk.y * kk.y + kk.z * kk.z + kk.w * kk.w;
                float xs[4] = {vv.x * mval, vv.y * mval, vv.z * mval, vv.w * mval};
#pragma unroll
                for (int e = 0; e < 4; ++e) {
                    int d = dq * 16 + j * 4 + e;
                    short hi, lo;
                    bfsplit(xs[e], hi, lo);
                    vTh[d * 136 + tlv] = hi;
                    vTl[d * 136 + tlv] = lo;
                }
            }
            np[dq * 128 + tlv] = s2;
        }
        __syncthreads();
        if (tid < 128) {
            norm_l[tid] = 0.5f * (np[tid] + np[128 + tid] + np[256 + tid] + np[384 + tid]);
            msk_l[tid]  = mg[b * T_ + t0 + tid] * SCALE_;
        }
        __syncthreads();

        // ---- proj: pr[m][n]; rows t = t0+tg*64+m*16+{l15|4q+j}, cols r = rg*64+n*16+l15 ----
        f32x4 pr[4][4];
#pragma unroll
        for (int m = 0; m < 4; ++m)
#pragma unroll
            for (int n = 0; n < 4; ++n) { f32x4 z4 = {0.f,0.f,0.f,0.f}; pr[m][n] = z4; }

#pragma unroll
        for (int w = 0; w < 2; ++w) {   // 32-d K windows
            h16x8 ah[4], al[4];
#pragma unroll
            for (int m = 0; m < 4; ++m) {
                const float* arow = kg + (rowb + t0 + tg * 64 + m * 16 + l15) * 64 + w * 32 + q * 4;
                float4 x0 = *(const float4*)arow;
                float4 x1 = *(const float4*)(arow + 16);
                h16x8 hv, lv;
                hv[0] = (h16)x0.x; hv[1] = (h16)x0.y; hv[2] = (h16)x0.z; hv[3] = (h16)x0.w;
                hv[4] = (h16)x1.x; hv[5] = (h16)x1.y; hv[6] = (h16)x1.z; hv[7] = (h16)x1.w;
                lv[0] = (h16)(x0.x - (float)hv[0]); lv[1] = (h16)(x0.y - (float)hv[1]);
                lv[2] = (h16)(x0.z - (float)hv[2]); lv[3] = (h16)(x0.w - (float)hv[3]);
                lv[4] = (h16)(x1.x - (float)hv[4]); lv[5] = (h16)(x1.y - (float)hv[5]);
                lv[6] = (h16)(x1.z - (float)hv[6]); lv[7] = (h16)(x1.w - (float)hv[7]);
                ah[m] = hv; al[m] = lv;
            }
            h16x8 wbh[4], wbl[4];
#pragma unroll
            for (int n = 0; n < 4; ++n) {
                int base = (rg * 64 + n * 16 + l15) * 72 + w * 32 + q * 4;
                h16x4 a0 = *(const h16x4*)&Wt[base];
                h16x4 a1 = *(const h16x4*)&Wt[base + 16];
                h16x4 b0 = *(const h16x4*)&Wt[256 * 72 + base];
                h16x4 b1 = *(const h16x4*)&Wt[256 * 72 + base + 16];
                h16x8 hv, lv;
                hv[0]=a0.x; hv[1]=a0.y; hv[2]=a0.z; hv[3]=a0.w; hv[4]=a1.x; hv[5]=a1.y; hv[6]=a1.z; hv[7]=a1.w;
                lv[0]=b0.x; lv[1]=b0.y; lv[2]=b0.z; lv[3]=b0.w; lv[4]=b1.x; lv[5]=b1.y; lv[6]=b1.z; lv[7]=b1.w;
                wbh[n] = hv; wbl[n] = lv;
            }
#pragma unroll
            for (int m = 0; m < 4; ++m)
#pragma unroll
                for (int n = 0; n < 4; ++n) {
                    pr[m][n] = __builtin_amdgcn_mfma_f32_16x16x32_f16(ah[m], wbh[n], pr[m][n], 0, 0, 0);
                    pr[m][n] = __builtin_amdgcn_mfma_f32_16x16x32_f16(ah[m], wbl[n], pr[m][n], 0, 0, 0);
                    pr[m][n] = __builtin_amdgcn_mfma_f32_16x16x32_f16(al[m], wbh[n], pr[m][n], 0, 0, 0);
                }
        }

        // ---- per 32-t window: exp -> bf16 split A-frags -> kv MFMA ----
#pragma unroll
        for (int W = 0; W < 2; ++W) {
            bf16x8 afh[4], afl[4];
#pragma unroll
            for (int n = 0; n < 4; ++n) {
                float ee[8];
#pragma unroll
                for (int half = 0; half < 2; ++half) {
                    int m = 2 * W + half;
                    int tl = tg * 64 + m * 16 + q * 4;
#pragma unroll
                    for (int j = 0; j < 4; ++j) {
                        float e = __expf(pr[m][n][j] - norm_l[tl + j]) * msk_l[tl + j];
                        ksa[n] += e;
                        ee[half * 4 + j] = e;
                    }
                }
                unsigned r0,r1,r2,r3,r4,r5,r6,r7;
                unsigned h01 = pk_hi2(ee[0], ee[1], r0, r1);
                unsigned h23 = pk_hi2(ee[2], ee[3], r2, r3);
                unsigned h45 = pk_hi2(ee[4], ee[5], r4, r5);
                unsigned h67 = pk_hi2(ee[6], ee[7], r6, r7);
                unsigned l01 = pk_tr2(ee[0]-__uint_as_float(r0), ee[1]-__uint_as_float(r1));
                unsigned l23 = pk_tr2(ee[2]-__uint_as_float(r2), ee[3]-__uint_as_float(r3));
                unsigned l45 = pk_tr2(ee[4]-__uint_as_float(r4), ee[5]-__uint_as_float(r5));
                unsigned l67 = pk_tr2(ee[6]-__uint_as_float(r6), ee[7]-__uint_as_float(r7));
                afh[n] = mkbf8(h01, h23, h45, h67);
                afl[n] = mkbf8(l01, l23, l45, l67);
            }
            bf16x8 bvh[4], bvl[4];
#pragma unroll
            for (int nd = 0; nd < 4; ++nd) {
                int base = (nd * 16 + l15) * 136 + tg * 64 + W * 32 + q * 4;
                short4v a0 = *(const short4v*)&vTh[base];
                short4v a1 = *(const short4v*)&vTh[base + 16];
                short4v b0 = *(const short4v*)&vTl[base];
                short4v b1 = *(const short4v*)&vTl[base + 16];
                bf16x8 hv, lv;
                hv[0]=a0.x; hv[1]=a0.y; hv[2]=a0.z; hv[3]=a0.w; hv[4]=a1.x; hv[5]=a1.y; hv[6]=a1.z; hv[7]=a1.w;
                lv[0]=b0.x; lv[1]=b0.y; lv[2]=b0.z; lv[3]=b0.w; lv[4]=b1.x; lv[5]=b1.y; lv[6]=b1.z; lv[7]=b1.w;
                bvh[nd] = hv; bvl[nd] = lv;
            }
#pragma unroll
            for (int n = 0; n < 4; ++n)
#pragma unroll
                for (int nd = 0; nd < 4; ++nd) {
                    kva[n][nd] = __builtin_amdgcn_mfma_f32_16x16x32_bf16(afh[n], bvh[nd], kva[n][nd], 0, 0, 0);
                    kva[n][nd] = __builtin_amdgcn_mfma_f32_16x16x32_bf16(afh[n], bvl[nd], kva[n][nd], 0, 0, 0);
                    kva[n][nd] = __builtin_amdgcn_mfma_f32_16x16x32_bf16(afl[n], bvh[nd], kva[n][nd], 0, 0, 0);
                }
        }
    }

    // ---- block end: all Wt/vT reads done -> red (alias Wt) usable ----
    __syncthreads();
#pragma unroll
    for (int n = 0; n < 4; ++n) {      // ksum: sum over q (t-quadrants)
        float v = ksa[n];
        v += __shfl_xor(v, 16);
        v += __shfl_xor(v, 32);
        if (q == 0) ksb[tg * 256 + rg * 64 + n * 16 + l15] = v;
    }
    if (tg == 0) {
#pragma unroll
        for (int n = 0; n < 4; ++n)
#pragma unroll
            for (int nd = 0; nd < 4; ++nd)
#pragma unroll
                for (int j = 0; j < 4; ++j)
                    red[(rg * 64 + n * 16 + q * 4 + j) * 68 + nd * 16 + l15] = kva[n][nd][j];
    }
    __syncthreads();
    if (tg == 1) {
#pragma unroll
        for (int n = 0; n < 4; ++n)
#pragma unroll
            for (int nd = 0; nd < 4; ++nd)
#pragma unroll
                for (int j = 0; j < 4; ++j)
                    red[(rg * 64 + n * 16 + q * 4 + j) * 68 + nd * 16 + l15] += kva[n][nd][j];
    }
    __syncthreads();
    {
        float* dst = kv_part + (long)(s * BH_ + bh) * (256 * 64);
#pragma unroll
        for (int i = 0; i < 8; ++i) {
            int flat = (i * 512 + tid) * 4;
            int r = flat >> 6, d = flat & 63;
            *(float4*)(dst + flat) = *(const float4*)&red[r * 68 + d];
        }
        if (tid < 256) ks_part[(long)(s * BH_ + bh) * 256 + tid] = ksb[tid] + ksb[256 + tid];
    }
}

// ============================================================
// Reduce: sum split partials; emit kv^T bf16 hi/lo [bh][pl][64 d][264 r]
// + ksum_f.  grid(8, BH), 256 thr — each block: 32 r-rows of one head.
// ============================================================
__global__ __launch_bounds__(256)
void k_reduce(const float* __restrict__ kvp, const float* __restrict__ ksp,
              short* __restrict__ kvt, float* __restrict__ ksf, int split)
{
    __shared__ __align__(16) float red2[32 * 68];
    const int tid = threadIdx.x, rq = blockIdx.x, bh = blockIdx.y;
    const long NKV4 = (long)BH_ * 256 * 64 / 4;
#pragma unroll
    for (int i = 0; i < 2; ++i) {
        int idx4 = i * 256 + tid;
        long g = (long)bh * 4096 + rq * 512 + idx4;
        float4 a = ((const float4*)kvp)[g];
        for (int p = 1; p < split; ++p) {
            float4 t = ((const float4*)kvp)[(long)p * NKV4 + g];
            a.x += t.x; a.y += t.y; a.z += t.z; a.w += t.w;
        }
        int flat = idx4 * 4;
        int rl = flat >> 6, d = flat & 63;
        *(float4*)&red2[rl * 68 + d] = a;
    }
    if (tid < 32) {
        float s = 0.f;
        for (int p = 0; p < split; ++p) s += ksp[(long)p * (BH_ * 256) + bh * 256 + rq * 32 + tid];
        ksf[bh * 256 + rq * 32 + tid] = s;
    }
    __syncthreads();
    short* dh = kvt + (long)bh * 33792;
    short* dl = dh + 16896;
#pragma unroll
    for (int i = 0; i < 8; ++i) {
        int flat = i * 256 + tid;
        int d = flat >> 5, rl = flat & 31;
        short h, l;
        bfsplit(red2[rl * 68 + d], h, l);
        dh[d * 264 + rq * 32 + rl] = h;
        dl[d * 264 + rq * 32 + rl] = l;
    }
}

// ============================================================
// Stage 2 (round-2 structure): per (128-t tile, head): proj^T = W^T q^T
// (f16x3) -> exp (+z via ksum) -> out = q' kv (bf16x3) -> sequential
// r-strip reduce -> divide by z+eps. 8 waves: (tt 0..1) x (rs 0..3).
// grid(32, BH), 512 thr.
// ============================================================
__global__ __launch_bounds__(512, 2)
void k_stage2(const float* __restrict__ qg, const h16* __restrict__ wtp,
              const short* __restrict__ kvt, const float* __restrict__ ksf,
              float* __restrict__ outg)
{
    __shared__ __align__(16) char smem[144384];
    h16*   Wt     = (h16*)smem;                       // [2][256*72]  73728 B
    short* kvTh   = (short*)(smem + 73728);           // [64*264]     33792 B
    short* kvTl   = kvTh + 64 * 264;                  // [64*264]     33792 B
    float* ksum_l = (float*)(smem + 73728 + 67584);   // [256]         1024 B
    float* zb     = ksum_l + 256;                     // [4][128]      2048 B
    float* red    = (float*)smem;                     // alias Wt (dead after proj)

    const int tid  = threadIdx.x;
    const int lane = tid & 63, l15 = lane & 15, q = lane >> 4;
    const int wid  = tid >> 6;
    const int rs = wid & 3, tt = wid >> 2;
    const int bh = blockIdx.y, t0 = blockIdx.x * 128;
    const long rowb = (long)bh * T_;

    {
        const float4* src = (const float4*)wtp;
        float4* dst = (float4*)Wt;
#pragma unroll
        for (int i = 0; i < 9; ++i) dst[i * 512 + tid] = src[i * 512 + tid];
        const float4* s2p = (const float4*)(kvt + (long)bh * 33792);
        float4* d2 = (float4*)kvTh;
#pragma unroll
        for (int i = 0; i < 9; ++i) { int idx = i * 512 + tid; if (idx < 4224) d2[idx] = s2p[idx]; }
        if (tid < 256) ksum_l[tid] = ksf[bh * 256 + tid];
    }
    __syncthreads();

    // ---- proj^T: rows r = rs*64+m*16+{l15|4q+j}, cols t = t0+tt*64+n*16+l15 ----
    f32x4 pr[4][4];
#pragma unroll
    for (int m = 0; m < 4; ++m)
#pragma unroll
        for (int n = 0; n < 4; ++n) { f32x4 z4 = {0.f,0.f,0.f,0.f}; pr[m][n] = z4; }
    float nacc[4] = {0.f, 0.f, 0.f, 0.f};

#pragma unroll
    for (int w = 0; w < 2; ++w) {
        h16x8 aWh[4], aWl[4];
#pragma unroll
        for (int m = 0; m < 4; ++m) {
            int base = (rs * 64 + m * 16 + l15) * 72 + w * 32 + q * 4;
            h16x4 a0 = *(const h16x4*)&Wt[base];
            h16x4 a1 = *(const h16x4*)&Wt[base + 16];
            h16x4 b0 = *(const h16x4*)&Wt[256 * 72 + base];
            h16x4 b1 = *(const h16x4*)&Wt[256 * 72 + base + 16];
            h16x8 hv, lv;
            hv[0]=a0.x; hv[1]=a0.y; hv[2]=a0.z; hv[3]=a0.w; hv[4]=a1.x; hv[5]=a1.y; hv[6]=a1.z; hv[7]=a1.w;
            lv[0]=b0.x; lv[1]=b0.y; lv[2]=b0.z; lv[3]=b0.w; lv[4]=b1.x; lv[5]=b1.y; lv[6]=b1.z; lv[7]=b1.w;
            aWh[m] = hv; aWl[m] = lv;
        }
        h16x8 qbh[4], qbl[4];
#pragma unroll
        for (int n = 0; n < 4; ++n) {
            const float* qrow = qg + (rowb + t0 + tt * 64 + n * 16 + l15) * 64 + w * 32 + q * 4;
            float4 x0 = *(const float4*)qrow;
            float4 x1 = *(const float4*)(qrow + 16);
            nacc[n] += x0.x * x0.x + x0.y * x0.y + x0.z * x0.z + x0.w * x0.w
                     + x1.x * x1.x + x1.y * x1.y + x1.z * x1.z + x1.w * x1.w;
            h16x8 hv, lv;
            hv[0] = (h16)x0.x; hv[1] = (h16)x0.y; hv[2] = (h16)x0.z; hv[3] = (h16)x0.w;
            hv[4] = (h16)x1.x; hv[5] = (h16)x1.y; hv[6] = (h16)x1.z; hv[7] = (h16)x1.w;
            lv[0] = (h16)(x0.x - (float)hv[0]); lv[1] = (h16)(x0.y - (float)hv[1]);
            lv[2] = (h16)(x0.z - (float)hv[2]); lv[3] = (h16)(x0.w - (float)hv[3]);
            lv[4] = (h16)(x1.x - (float)hv[4]); lv[5] = (h16)(x1.y - (float)hv[5]);
            lv[6] = (h16)(x1.z - (float)hv[6]); lv[7] = (h16)(x1.w - (float)hv[7]);
            qbh[n] = hv; qbl[n] = lv;
        }
#pragma unroll
        for (int m = 0; m < 4; ++m)
#pragma unroll
            for (int n = 0; n < 4; ++n) {
                pr[m][n] = __builtin_amdgcn_mfma_f32_16x16x32_f16(aWh[m], qbh[n], pr[m][n], 0, 0, 0);
                pr[m][n] = __builtin_amdgcn_mfma_f32_16x16x32_f16(aWh[m], qbl[n], pr[m][n], 0, 0, 0);
                pr[m][n] = __builtin_amdgcn_mfma_f32_16x16x32_f16(aWl[m], qbh[n], pr[m][n], 0, 0, 0);
            }
    }
    float normt[4];
#pragma unroll
    for (int n = 0; n < 4; ++n) {
        float v = nacc[n];
        v += __shfl_xor(v, 16);
        v += __shfl_xor(v, 32);
        normt[n] = 0.5f * v;
    }

    // ---- exp + z + out-GEMM per 32-r window ----
    f32x4 oac[4][4];
#pragma unroll
    for (int n = 0; n < 4; ++n)
#pragma unroll
        for (int nd = 0; nd < 4; ++nd) { f32x4 z4 = {0.f,0.f,0.f,0.f}; oac[n][nd] = z4; }
    float zp[4] = {0.f, 0.f, 0.f, 0.f};

#pragma unroll
    for (int W = 0; W < 2; ++W) {
        bf16x8 aph[4], apl[4];
#pragma unroll
        for (int n = 0; n < 4; ++n) {
            float ee[8];
#pragma unroll
            for (int half = 0; half < 2; ++half) {
                int m = 2 * W + half;
                int rl = rs * 64 + m * 16 + q * 4;
#pragma unroll
                for (int j = 0; j < 4; ++j) {
                    float e = __expf(pr[m][n][j] - normt[n]) * SCALE_;
                    zp[n] += e * ksum_l[rl + j];
                    ee[half * 4 + j] = e;
                }
            }
            unsigned r0,r1,r2,r3,r4,r5,r6,r7;
            unsigned h01 = pk_hi2(ee[0], ee[1], r0, r1);
            unsigned h23 = pk_hi2(ee[2], ee[3], r2, r3);
            unsigned h45 = pk_hi2(ee[4], ee[5], r4, r5);
            unsigned h67 = pk_hi2(ee[6], ee[7], r6, r7);
            unsigned l01 = pk_tr2(ee[0]-__uint_as_float(r0), ee[1]-__uint_as_float(r1));
            unsigned l23 = pk_tr2(ee[2]-__uint_as_float(r2), ee[3]-__uint_as_float(r3));
            unsigned l45 = pk_tr2(ee[4]-__uint_as_float(r4), ee[5]-__uint_as_float(r5));
            unsigned l67 = pk_tr2(ee[6]-__uint_as_float(r6), ee[7]-__uint_as_float(r7));
            aph[n] = mkbf8(h01, h23, h45, h67);
            apl[n] = mkbf8(l01, l23, l45, l67);
        }
        bf16x8 bkh[4], bkl[4];
#pragma unroll
        for (int nd = 0; nd < 4; ++nd) {
            int d  = nd * 16 + l15;
            int rb = rs * 64 + W * 32 + q * 4;
            short4v a0 = *(const short4v*)&kvTh[d * 264 + rb];
            short4v a1 = *(const short4v*)&kvTh[d * 264 + rb + 16];
            short4v b0 = *(const short4v*)&kvTl[d * 264 + rb];
            short4v b1 = *(const short4v*)&kvTl[d * 264 + rb + 16];
            bf16x8 hv, lv;
            hv[0]=a0.x; hv[1]=a0.y; hv[2]=a0.z; hv[3]=a0.w; hv[4]=a1.x; hv[5]=a1.y; hv[6]=a1.z; hv[7]=a1.w;
            lv[0]=b0.x; lv[1]=b0.y; lv[2]=b0.z; lv[3]=b0.w; lv[4]=b1.x; lv[5]=b1.y; lv[6]=b1.z; lv[7]=b1.w;
            bkh[nd] = hv; bkl[nd] = lv;
        }
#pragma unroll
        for (int n = 0; n < 4; ++n)
#pragma unroll
            for (int nd = 0; nd < 4; ++nd) {
                oac[n][nd] = __builtin_amdgcn_mfma_f32_16x16x32_bf16(aph[n], bkh[nd], oac[n][nd], 0, 0, 0);
                oac[n][nd] = __builtin_amdgcn_mfma_f32_16x16x32_bf16(aph[n], bkl[nd], oac[n][nd], 0, 0, 0);
                oac[n][nd] = __builtin_amdgcn_mfma_f32_16x16x32_bf16(apl[n], bkh[nd], oac[n][nd], 0, 0, 0);
            }
    }
#pragma unroll
    for (int n = 0; n < 4; ++n) {   // z partials (sum over r-quadrants)
        float v = zp[n];
        v += __shfl_xor(v, 16);
        v += __shfl_xor(v, 32);
        if (q == 0) zb[rs * 128 + tt * 64 + n * 16 + l15] = v;
    }
    __syncthreads();   // all proj reads of Wt done -> red (alias) writable; zb visible

    // ---- sequential reduce over r-strips into red ----
#pragma unroll
    for (int p = 0; p < 4; ++p) {
        if (rs == p) {
#pragma unroll
            for (int n = 0; n < 4; ++n)
#pragma unroll
                for (int nd = 0; nd < 4; ++nd)
#pragma unroll
                    for (int j = 0; j < 4; ++j) {
                        int idx = (tt * 64 + n * 16 + q * 4 + j) * 68 + nd * 16 + l15;
                        if (p == 0) red[idx] = oac[n][nd][j];
                        else        red[idx] += oac[n][nd][j];
                    }
        }
        __syncthreads();
    }

    // ---- epilogue: divide by z+eps, store ----
#pragma unroll
    for (int i = 0; i < 4; ++i) {
        int flat = i * 2048 + tid * 4;
        int tl = flat >> 6, d = flat & 63;
        float z = zb[0 * 128 + tl] + zb[1 * 128 + tl] + zb[2 * 128 + tl] + zb[3 * 128 + tl] + EPS_;
        float rz = 1.f / z;
        float4 o = *(const float4*)&red[tl * 68 + d];
        o.x *= rz; o.y *= rz; o.z *= rz; o.w *= rz;
        *(float4*)&outg[(rowb + t0 + tl) * 64 + d] = o;
    }
}

// ============================================================
extern "C" void kernel_launch(void* const* d_in, const int* in_sizes, int n_in,
                              void* d_out, int out_size, void* d_ws, size_t ws_size,
                              hipStream_t stream)
{
    const float* q  = (const float*)d_in[0];
    const float* k  = (const float*)d_in[1];
    const float* v  = (const float*)d_in[2];
    const float* m  = (const float*)d_in[3];
    const float* W  = (const float*)d_in[4];
    float* out = (float*)d_out;

    char* ws = (char*)d_ws;
    h16*   wtp = (h16*)ws;                                   // 73728 B
    short* kvt = (short*)(ws + 73728);                       // 4325376 B
    float* ksf = (float*)(ws + 73728 + 4325376);             // 65536 B

    int split = 8;
    while (split > 1) {
        size_t need = 73728ull + 4325376ull + 65536ull
                    + (size_t)split * (4194304ull + 65536ull);
        if (need <= ws_size) break;
        split >>= 1;
    }
    float* kvp = (float*)(ws + 73728 + 4325376 + 65536);
    float* ksp = kvp + (size_t)split * (256 * 64 * BH_);
    int nch = (T_ / split) / 128;

    k_prep  <<<dim3(64),          dim3(256), 0, stream>>>(W, wtp);
    k_stage1<<<dim3(split, BH_),  dim3(512), 0, stream>>>(k, v, m, wtp, kvp, ksp, nch);
    k_reduce<<<dim3(8, BH_),      dim3(256), 0, stream>>>(kvp, ksp, kvt, ksf, split);
    k_stage2<<<dim3(T_ / 128, BH_), dim3(512), 0, stream>>>(q, wtp, kvt, ksf, out);
}

// Round 9
// 326.132 us; speedup vs baseline: 2.8171x; 1.0040x over previous
//
#include <hip/hip_runtime.h>
#include <math.h>

#define T_     4096
#define BH_    64
#define EPS_   1e-6f
#define SCALE_ 0.0625f   // 1/sqrt(256)

typedef _Float16 h16;
typedef __attribute__((ext_vector_type(4))) _Float16 h16x4;
typedef __attribute__((ext_vector_type(8))) _Float16 h16x8;
typedef __attribute__((ext_vector_type(4))) short    short4v;
typedef __attribute__((ext_vector_type(8))) short    bf16x8;
typedef __attribute__((ext_vector_type(4))) float    f32x4;
typedef __attribute__((ext_vector_type(4))) unsigned uint4v;

__device__ __forceinline__ void bfsplit(float x, short& h, short& l) {
    unsigned u = __float_as_uint(x) + 0x8000u;       // round-half-up to bf16
    unsigned hb = u & 0xffff0000u;
    h = (short)(u >> 16);
    float lf = x - __uint_as_float(hb);              // exact residual
    l = (short)(__float_as_uint(lf) >> 16);          // truncated residual
}
// pack bf16(a) (low) | bf16(b) (high), round-half-up; returns residual bit patterns
__device__ __forceinline__ unsigned pk_hi2(float a, float b, unsigned& ra, unsigned& rb) {
    unsigned ua = __float_as_uint(a) + 0x8000u;
    unsigned ub = __float_as_uint(b) + 0x8000u;
    ra = ua & 0xffff0000u; rb = ub & 0xffff0000u;
    return __builtin_amdgcn_perm(ub, ua, 0x07060302u);
}
__device__ __forceinline__ unsigned pk_tr2(float a, float b) {   // truncating pack
    return __builtin_amdgcn_perm(__float_as_uint(b), __float_as_uint(a), 0x07060302u);
}
__device__ __forceinline__ bf16x8 mkbf8(unsigned a, unsigned b, unsigned c, unsigned d) {
    uint4v t; t.x = a; t.y = b; t.z = c; t.w = d;
    return __builtin_bit_cast(bf16x8, t);
}

// ============================================================
// prep: W (64x256) -> MFMA-fragment-ordered f16 hi/lo planes wfg:
//   frag(r, w, q)[8] = W^T[r][w*32+q*4 .. +3] ++ W^T[r][w*32+16+q*4 .. +3]
//   hi plane at [0, 16384) h16, lo plane at +16384. (HW-validated r7.)
// ============================================================
__global__ __launch_bounds__(256)
void k_prep(const float* __restrict__ Wg, h16* __restrict__ wfg)
{
    int d = blockIdx.x;      // 0..63
    int r = threadIdx.x;     // 0..255
    float x = Wg[d * 256 + r];
    h16 hi = (h16)x;
    h16 lo = (h16)(x - (float)hi);
    int w = d >> 5, rem = d & 31;
    int half = rem >> 4, qq = (rem >> 2) & 3, i = rem & 3;
    int dst = (r * 8 + w * 4 + qq) * 8 + half * 4 + i;
    wfg[dst]         = hi;
    wfg[16384 + dst] = lo;
}

// ============================================================
// Stage 1: per (t-chunk s, head bh): stage v^T + k norms -> proj_k
// (f16x3, k from global, W frags from global/L2) -> exp -> kv (bf16x3).
// 8 waves: (tg 0..1) x (rg 0..3). LDS 56 KB -> 2 blocks/CU.
// Block end: cross-tg reduce via 17-KB quarter buffer.
// ============================================================
__global__ __launch_bounds__(512, 2)
void k_stage1(const float* __restrict__ kg, const float* __restrict__ vg,
              const float* __restrict__ mg, const h16* __restrict__ wfg,
              float* __restrict__ kv_part, float* __restrict__ ks_part, int nch)
{
    __shared__ __align__(16) char smem[57344];
    short* vTh    = (short*)smem;                   // [64*136] 17408 B
    short* vTl    = (short*)(smem + 17408);         // [64*136] 17408 B
    float* redq   = (float*)(smem + 34816);         // [64*68]  17408 B
    float* np     = (float*)(smem + 52224);         // [4][128]  2048 B
    float* norm_l = (float*)(smem + 54272);         // [128]      512 B
    float* msk_l  = (float*)(smem + 54784);         // [128]      512 B
    float* ksb    = (float*)(smem + 55296);         // [2][256]  2048 B

    const int tid  = threadIdx.x;
    const int lane = tid & 63, l15 = lane & 15, q = lane >> 4;
    const int wid  = tid >> 6;
    const int rg = wid & 3, tg = wid >> 2;
    const int s = blockIdx.x, bh = blockIdx.y, b = bh >> 4;
    const long rowb = (long)bh * T_;

    f32x4 kva[4][4];
#pragma unroll
    for (int a = 0; a < 4; ++a)
#pragma unroll
        for (int c2 = 0; c2 < 4; ++c2) { f32x4 z4 = {0.f,0.f,0.f,0.f}; kva[a][c2] = z4; }
    float ksa[4] = {0.f, 0.f, 0.f, 0.f};

    for (int c = 0; c < nch; ++c) {
        const int t0 = (s * nch + c) * 128;
        __syncthreads();   // prev chunk fully consumed

        // ---- stage v^T (mask-scaled, bf16 hi/lo) + k row-norm partials ----
        {
            const int tlv = tid & 127, dq = tid >> 7;
            const float mval = mg[b * T_ + t0 + tlv];
            const float* vrow = vg + (rowb + t0 + tlv) * 64 + dq * 16;
            const float* krow = kg + (rowb + t0 + tlv) * 64 + dq * 16;
            float s2 = 0.f;
#pragma unroll
            for (int j = 0; j < 4; ++j) {
                float4 vv = *(const float4*)(vrow + j * 4);
                float4 kk = *(const float4*)(krow + j * 4);
                s2 += kk.x * kk.x + kk.y * kk.y + kk.z * kk.z + kk.w * kk.w;
                float xs[4] = {vv.x * mval, vv.y * mval, vv.z * mval, vv.w * mval};
#pragma unroll
                for (int e = 0; e < 4; ++e) {
                    int d = dq * 16 + j * 4 + e;
                    short hi, lo;
                    bfsplit(xs[e], hi, lo);
                    vTh[d * 136 + tlv] = hi;
                    vTl[d * 136 + tlv] = lo;
                }
            }
            np[dq * 128 + tlv] = s2;
        }
        __syncthreads();
        if (tid < 128) {
            norm_l[tid] = 0.5f * (np[tid] + np[128 + tid] + np[256 + tid] + np[384 + tid]);
            msk_l[tid]  = mg[b * T_ + t0 + tid] * SCALE_;
        }
        __syncthreads();

        // ---- proj: pr[m][n]; rows t = t0+tg*64+m*16+{l15|4q+j}, cols r = rg*64+n*16+l15 ----
        f32x4 pr[4][4];
#pragma unroll
        for (int m = 0; m < 4; ++m)
#pragma unroll
            for (int n = 0; n < 4; ++n) { f32x4 z4 = {0.f,0.f,0.f,0.f}; pr[m][n] = z4; }

#pragma unroll
        for (int w = 0; w < 2; ++w) {   // 32-d K windows
            h16x8 ah[4], al[4];
#pragma unroll
            for (int m = 0; m < 4; ++m) {
                const float* arow = kg + (rowb + t0 + tg * 64 + m * 16 + l15) * 64 + w * 32 + q * 4;
                float4 x0 = *(const float4*)arow;
                float4 x1 = *(const float4*)(arow + 16);
                h16x8 hv, lv;
                hv[0] = (h16)x0.x; hv[1] = (h16)x0.y; hv[2] = (h16)x0.z; hv[3] = (h16)x0.w;
                hv[4] = (h16)x1.x; hv[5] = (h16)x1.y; hv[6] = (h16)x1.z; hv[7] = (h16)x1.w;
                lv[0] = (h16)(x0.x - (float)hv[0]); lv[1] = (h16)(x0.y - (float)hv[1]);
                lv[2] = (h16)(x0.z - (float)hv[2]); lv[3] = (h16)(x0.w - (float)hv[3]);
                lv[4] = (h16)(x1.x - (float)hv[4]); lv[5] = (h16)(x1.y - (float)hv[5]);
                lv[6] = (h16)(x1.z - (float)hv[6]); lv[7] = (h16)(x1.w - (float)hv[7]);
                ah[m] = hv; al[m] = lv;
            }
            h16x8 wbh[4], wbl[4];
#pragma unroll
            for (int n = 0; n < 4; ++n) {
                int fb = ((rg * 64 + n * 16 + l15) * 8 + w * 4 + q) * 8;
                wbh[n] = *(const h16x8*)&wfg[fb];
                wbl[n] = *(const h16x8*)&wfg[16384 + fb];
            }
#pragma unroll
            for (int m = 0; m < 4; ++m)
#pragma unroll
                for (int n = 0; n < 4; ++n) {
                    pr[m][n] = __builtin_amdgcn_mfma_f32_16x16x32_f16(ah[m], wbh[n], pr[m][n], 0, 0, 0);
                    pr[m][n] = __builtin_amdgcn_mfma_f32_16x16x32_f16(ah[m], wbl[n], pr[m][n], 0, 0, 0);
                    pr[m][n] = __builtin_amdgcn_mfma_f32_16x16x32_f16(al[m], wbh[n], pr[m][n], 0, 0, 0);
                }
        }

        // ---- per 32-t window: exp -> bf16 split A-frags -> kv MFMA ----
#pragma unroll
        for (int W = 0; W < 2; ++W) {
            bf16x8 afh[4], afl[4];
#pragma unroll
            for (int n = 0; n < 4; ++n) {
                float ee[8];
#pragma unroll
                for (int half = 0; half < 2; ++half) {
                    int m = 2 * W + half;
                    int tl = tg * 64 + m * 16 + q * 4;
#pragma unroll
                    for (int j = 0; j < 4; ++j) {
                        float e = __expf(pr[m][n][j] - norm_l[tl + j]) * msk_l[tl + j];
                        ksa[n] += e;
                        ee[half * 4 + j] = e;
                    }
                }
                unsigned r0,r1,r2,r3,r4,r5,r6,r7;
                unsigned h01 = pk_hi2(ee[0], ee[1], r0, r1);
                unsigned h23 = pk_hi2(ee[2], ee[3], r2, r3);
                unsigned h45 = pk_hi2(ee[4], ee[5], r4, r5);
                unsigned h67 = pk_hi2(ee[6], ee[7], r6, r7);
                unsigned l01 = pk_tr2(ee[0]-__uint_as_float(r0), ee[1]-__uint_as_float(r1));
                unsigned l23 = pk_tr2(ee[2]-__uint_as_float(r2), ee[3]-__uint_as_float(r3));
                unsigned l45 = pk_tr2(ee[4]-__uint_as_float(r4), ee[5]-__uint_as_float(r5));
                unsigned l67 = pk_tr2(ee[6]-__uint_as_float(r6), ee[7]-__uint_as_float(r7));
                afh[n] = mkbf8(h01, h23, h45, h67);
                afl[n] = mkbf8(l01, l23, l45, l67);
            }
            bf16x8 bvh[4], bvl[4];
#pragma unroll
            for (int nd = 0; nd < 4; ++nd) {
                int base = (nd * 16 + l15) * 136 + tg * 64 + W * 32 + q * 4;
                short4v a0 = *(const short4v*)&vTh[base];
                short4v a1 = *(const short4v*)&vTh[base + 16];
                short4v b0 = *(const short4v*)&vTl[base];
                short4v b1 = *(const short4v*)&vTl[base + 16];
                bf16x8 hv, lv;
                hv[0]=a0.x; hv[1]=a0.y; hv[2]=a0.z; hv[3]=a0.w; hv[4]=a1.x; hv[5]=a1.y; hv[6]=a1.z; hv[7]=a1.w;
                lv[0]=b0.x; lv[1]=b0.y; lv[2]=b0.z; lv[3]=b0.w; lv[4]=b1.x; lv[5]=b1.y; lv[6]=b1.z; lv[7]=b1.w;
                bvh[nd] = hv; bvl[nd] = lv;
            }
#pragma unroll
            for (int n = 0; n < 4; ++n)
#pragma unroll
                for (int nd = 0; nd < 4; ++nd) {
                    kva[n][nd] = __builtin_amdgcn_mfma_f32_16x16x32_bf16(afh[n], bvh[nd], kva[n][nd], 0, 0, 0);
                    kva[n][nd] = __builtin_amdgcn_mfma_f32_16x16x32_bf16(afh[n], bvl[nd], kva[n][nd], 0, 0, 0);
                    kva[n][nd] = __builtin_amdgcn_mfma_f32_16x16x32_bf16(afl[n], bvh[nd], kva[n][nd], 0, 0, 0);
                }
        }
    }

    // ---- block end: ksum + quarter-wise cross-tg kv reduce + store ----
#pragma unroll
    for (int n = 0; n < 4; ++n) {      // ksum: sum over q (t-quadrants)
        float v = ksa[n];
        v += __shfl_xor(v, 16);
        v += __shfl_xor(v, 32);
        if (q == 0) ksb[tg * 256 + rg * 64 + n * 16 + l15] = v;
    }
    const long pb = (long)(s * BH_ + bh) * (256 * 64);
#pragma unroll
    for (int p = 0; p < 4; ++p) {      // r-quarter [p*64, p*64+64)
        __syncthreads();               // redq free (prev quarter stored / loop entry)
        if (tg == 0 && rg == p) {
#pragma unroll
            for (int n = 0; n < 4; ++n)
#pragma unroll
                for (int nd = 0; nd < 4; ++nd)
#pragma unroll
                    for (int j = 0; j < 4; ++j)
                        redq[(n * 16 + q * 4 + j) * 68 + nd * 16 + l15] = kva[n][nd][j];
        }
        __syncthreads();
        if (tg == 1 && rg == p) {
#pragma unroll
            for (int n = 0; n < 4; ++n)
#pragma unroll
                for (int nd = 0; nd < 4; ++nd)
#pragma unroll
                    for (int j = 0; j < 4; ++j)
                        redq[(n * 16 + q * 4 + j) * 68 + nd * 16 + l15] += kva[n][nd][j];
        }
        __syncthreads();
        {
            float* dst = kv_part + pb + p * 64 * 64;
#pragma unroll
            for (int i = 0; i < 2; ++i) {
                int idx4 = i * 512 + tid;
                int row = idx4 >> 4, d4 = (idx4 & 15) << 2;
                *(float4*)(dst + row * 64 + d4) = *(const float4*)&redq[row * 68 + d4];
            }
        }
    }
    if (tid < 256) ks_part[(long)(s * BH_ + bh) * 256 + tid] = ksb[tid] + ksb[256 + tid];
}

// ============================================================
// Reduce: sum split partials; emit kv^T bf16 hi/lo [bh][pl][64 d][264 r]
// + ksum_f.  grid(8, BH), 256 thr — each block: 32 r-rows of one head.
// ============================================================
__global__ __launch_bounds__(256)
void k_reduce(const float* __restrict__ kvp, const float* __restrict__ ksp,
              short* __restrict__ kvt, float* __restrict__ ksf, int split)
{
    __shared__ __align__(16) float red2[32 * 68];
    const int tid = threadIdx.x, rq = blockIdx.x, bh = blockIdx.y;
    const long NKV4 = (long)BH_ * 256 * 64 / 4;
#pragma unroll
    for (int i = 0; i < 2; ++i) {
        int idx4 = i * 256 + tid;
        long g = (long)bh * 4096 + rq * 512 + idx4;
        float4 a = ((const float4*)kvp)[g];
        for (int p = 1; p < split; ++p) {
            float4 t = ((const float4*)kvp)[(long)p * NKV4 + g];
            a.x += t.x; a.y += t.y; a.z += t.z; a.w += t.w;
        }
        int flat = idx4 * 4;
        int rl = flat >> 6, d = flat & 63;
        *(float4*)&red2[rl * 68 + d] = a;
    }
    if (tid < 32) {
        float s = 0.f;
        for (int p = 0; p < split; ++p) s += ksp[(long)p * (BH_ * 256) + bh * 256 + rq * 32 + tid];
        ksf[bh * 256 + rq * 32 + tid] = s;
    }
    __syncthreads();
    short* dh = kvt + (long)bh * 33792;
    short* dl = dh + 16896;
#pragma unroll
    for (int i = 0; i < 8; ++i) {
        int flat = i * 256 + tid;
        int d = flat >> 5, rl = flat & 31;
        short h, l;
        bfsplit(red2[rl * 68 + d], h, l);
        dh[d * 264 + rq * 32 + rl] = h;
        dl[d * 264 + rq * 32 + rl] = l;
    }
}

// ============================================================
// Stage 2: per (128-t tile, head): proj^T = W^T q^T (f16x3, W frags
// from global/L2) -> exp (+z) -> out = q' kv (bf16x3) -> sequential
// r-strip reduce (red aliases dead kvT) -> divide. 8 waves: (tt,rs).
// LDS 69 KB -> 2 blocks/CU. grid(32, BH), 512 thr.
// ============================================================
__global__ __launch_bounds__(512, 2)
void k_stage2(const float* __restrict__ qg, const h16* __restrict__ wfg,
              const short* __restrict__ kvt, const float* __restrict__ ksf,
              float* __restrict__ outg)
{
    __shared__ __align__(16) char smem[70656];
    short* kvTh   = (short*)smem;                   // [64*264] 33792 B
    short* kvTl   = (short*)(smem + 33792);         // [64*264] 33792 B
    float* ksum_l = (float*)(smem + 67584);         // [256]     1024 B
    float* zb     = (float*)(smem + 68608);         // [4][128]  2048 B
    float* red    = (float*)smem;                   // alias kvT (dead after out-GEMM)

    const int tid  = threadIdx.x;
    const int lane = tid & 63, l15 = lane & 15, q = lane >> 4;
    const int wid  = tid >> 6;
    const int rs = wid & 3, tt = wid >> 2;
    const int bh = blockIdx.y, t0 = blockIdx.x * 128;
    const long rowb = (long)bh * T_;

    {
        const float4* s2p = (const float4*)(kvt + (long)bh * 33792);
        float4* d2 = (float4*)kvTh;
#pragma unroll
        for (int i = 0; i < 9; ++i) { int idx = i * 512 + tid; if (idx < 4224) d2[idx] = s2p[idx]; }
        if (tid < 256) ksum_l[tid] = ksf[bh * 256 + tid];
    }
    __syncthreads();

    // ---- proj^T: rows r = rs*64+m*16+{l15|4q+j}, cols t = t0+tt*64+n*16+l15 ----
    f32x4 pr[4][4];
#pragma unroll
    for (int m = 0; m < 4; ++m)
#pragma unroll
        for (int n = 0; n < 4; ++n) { f32x4 z4 = {0.f,0.f,0.f,0.f}; pr[m][n] = z4; }
    float nacc[4] = {0.f, 0.f, 0.f, 0.f};

#pragma unroll
    for (int w = 0; w < 2; ++w) {
        h16x8 aWh[4], aWl[4];
#pragma unroll
        for (int m = 0; m < 4; ++m) {
            int fb = ((rs * 64 + m * 16 + l15) * 8 + w * 4 + q) * 8;
            aWh[m] = *(const h16x8*)&wfg[fb];
            aWl[m] = *(const h16x8*)&wfg[16384 + fb];
        }
        h16x8 qbh[4], qbl[4];
#pragma unroll
        for (int n = 0; n < 4; ++n) {
            const float* qrow = qg + (rowb + t0 + tt * 64 + n * 16 + l15) * 64 + w * 32 + q * 4;
            float4 x0 = *(const float4*)qrow;
            float4 x1 = *(const float4*)(qrow + 16);
            nacc[n] += x0.x * x0.x + x0.y * x0.y + x0.z * x0.z + x0.w * x0.w
                     + x1.x * x1.x + x1.y * x1.y + x1.z * x1.z + x1.w * x1.w;
            h16x8 hv, lv;
            hv[0] = (h16)x0.x; hv[1] = (h16)x0.y; hv[2] = (h16)x0.z; hv[3] = (h16)x0.w;
            hv[4] = (h16)x1.x; hv[5] = (h16)x1.y; hv[6] = (h16)x1.z; hv[7] = (h16)x1.w;
            lv[0] = (h16)(x0.x - (float)hv[0]); lv[1] = (h16)(x0.y - (float)hv[1]);
            lv[2] = (h16)(x0.z - (float)hv[2]); lv[3] = (h16)(x0.w - (float)hv[3]);
            lv[4] = (h16)(x1.x - (float)hv[4]); lv[5] = (h16)(x1.y - (float)hv[5]);
            lv[6] = (h16)(x1.z - (float)hv[6]); lv[7] = (h16)(x1.w - (float)hv[7]);
            qbh[n] = hv; qbl[n] = lv;
        }
#pragma unroll
        for (int m = 0; m < 4; ++m)
#pragma unroll
            for (int n = 0; n < 4; ++n) {
                pr[m][n] = __builtin_amdgcn_mfma_f32_16x16x32_f16(aWh[m], qbh[n], pr[m][n], 0, 0, 0);
                pr[m][n] = __builtin_amdgcn_mfma_f32_16x16x32_f16(aWh[m], qbl[n], pr[m][n], 0, 0, 0);
                pr[m][n] = __builtin_amdgcn_mfma_f32_16x16x32_f16(aWl[m], qbh[n], pr[m][n], 0, 0, 0);
            }
    }
    float normt[4];
#pragma unroll
    for (int n = 0; n < 4; ++n) {
        float v = nacc[n];
        v += __shfl_xor(v, 16);
        v += __shfl_xor(v, 32);
        normt[n] = 0.5f * v;
    }

    // ---- exp + z + out-GEMM per 32-r window ----
    f32x4 oac[4][4];
#pragma unroll
    for (int n = 0; n < 4; ++n)
#pragma unroll
        for (int nd = 0; nd < 4; ++nd) { f32x4 z4 = {0.f,0.f,0.f,0.f}; oac[n][nd] = z4; }
    float zp[4] = {0.f, 0.f, 0.f, 0.f};

#pragma unroll
    for (int W = 0; W < 2; ++W) {
        bf16x8 aph[4], apl[4];
#pragma unroll
        for (int n = 0; n < 4; ++n) {
            float ee[8];
#pragma unroll
            for (int half = 0; half < 2; ++half) {
                int m = 2 * W + half;
                int rl = rs * 64 + m * 16 + q * 4;
#pragma unroll
                for (int j = 0; j < 4; ++j) {
                    float e = __expf(pr[m][n][j] - normt[n]) * SCALE_;
                    zp[n] += e * ksum_l[rl + j];
                    ee[half * 4 + j] = e;
                }
            }
            unsigned r0,r1,r2,r3,r4,r5,r6,r7;
            unsigned h01 = pk_hi2(ee[0], ee[1], r0, r1);
            unsigned h23 = pk_hi2(ee[2], ee[3], r2, r3);
            unsigned h45 = pk_hi2(ee[4], ee[5], r4, r5);
            unsigned h67 = pk_hi2(ee[6], ee[7], r6, r7);
            unsigned l01 = pk_tr2(ee[0]-__uint_as_float(r0), ee[1]-__uint_as_float(r1));
            unsigned l23 = pk_tr2(ee[2]-__uint_as_float(r2), ee[3]-__uint_as_float(r3));
            unsigned l45 = pk_tr2(ee[4]-__uint_as_float(r4), ee[5]-__uint_as_float(r5));
            unsigned l67 = pk_tr2(ee[6]-__uint_as_float(r6), ee[7]-__uint_as_float(r7));
            aph[n] = mkbf8(h01, h23, h45, h67);
            apl[n] = mkbf8(l01, l23, l45, l67);
        }
        bf16x8 bkh[4], bkl[4];
#pragma unroll
        for (int nd = 0; nd < 4; ++nd) {
            int d  = nd * 16 + l15;
            int rb = rs * 64 + W * 32 + q * 4;
            short4v a0 = *(const short4v*)&kvTh[d * 264 + rb];
            short4v a1 = *(const short4v*)&kvTh[d * 264 + rb + 16];
            short4v b0 = *(const short4v*)&kvTl[d * 264 + rb];
            short4v b1 = *(const short4v*)&kvTl[d * 264 + rb + 16];
            bf16x8 hv, lv;
            hv[0]=a0.x; hv[1]=a0.y; hv[2]=a0.z; hv[3]=a0.w; hv[4]=a1.x; hv[5]=a1.y; hv[6]=a1.z; hv[7]=a1.w;
            lv[0]=b0.x; lv[1]=b0.y; lv[2]=b0.z; lv[3]=b0.w; lv[4]=b1.x; lv[5]=b1.y; lv[6]=b1.z; lv[7]=b1.w;
            bkh[nd] = hv; bkl[nd] = lv;
        }
#pragma unroll
        for (int n = 0; n < 4; ++n)
#pragma unroll
            for (int nd = 0; nd < 4; ++nd) {
                oac[n][nd] = __builtin_amdgcn_mfma_f32_16x16x32_bf16(aph[n], bkh[nd], oac[n][nd], 0, 0, 0);
                oac[n][nd] = __builtin_amdgcn_mfma_f32_16x16x32_bf16(aph[n], bkl[nd], oac[n][nd], 0, 0, 0);
                oac[n][nd] = __builtin_amdgcn_mfma_f32_16x16x32_bf16(apl[n], bkh[nd], oac[n][nd], 0, 0, 0);
            }
    }
#pragma unroll
    for (int n = 0; n < 4; ++n) {   // z partials (sum over r-quadrants)
        float v = zp[n];
        v += __shfl_xor(v, 16);
        v += __shfl_xor(v, 32);
        if (q == 0) zb[rs * 128 + tt * 64 + n * 16 + l15] = v;
    }
    __syncthreads();   // all kvT reads done -> red (alias) writable; zb visible

    // ---- sequential reduce over r-strips into red ----
#pragma unroll
    for (int p = 0; p < 4; ++p) {
        if (rs == p) {
#pragma unroll
            for (int n = 0; n < 4; ++n)
#pragma unroll
                for (int nd = 0; nd < 4; ++nd)
#pragma unroll
                    for (int j = 0; j < 4; ++j) {
                        int idx = (tt * 64 + n * 16 + q * 4 + j) * 68 + nd * 16 + l15;
                        if (p == 0) red[idx] = oac[n][nd][j];
                        else        red[idx] += oac[n][nd][j];
                    }
        }
        __syncthreads();
    }

    // ---- epilogue: divide by z+eps, store ----
#pragma unroll
    for (int i = 0; i < 4; ++i) {
        int flat = i * 2048 + tid * 4;
        int tl = flat >> 6, d = flat & 63;
        float z = zb[0 * 128 + tl] + zb[1 * 128 + tl] + zb[2 * 128 + tl] + zb[3 * 128 + tl] + EPS_;
        float rz = 1.f / z;
        float4 o = *(const float4*)&red[tl * 68 + d];
        o.x *= rz; o.y *= rz; o.z *= rz; o.w *= rz;
        *(float4*)&outg[(rowb + t0 + tl) * 64 + d] = o;
    }
}

// ============================================================
extern "C" void kernel_launch(void* const* d_in, const int* in_sizes, int n_in,
                              void* d_out, int out_size, void* d_ws, size_t ws_size,
                              hipStream_t stream)
{
    const float* q  = (const float*)d_in[0];
    const float* k  = (const float*)d_in[1];
    const float* v  = (const float*)d_in[2];
    const float* m  = (const float*)d_in[3];
    const float* W  = (const float*)d_in[4];
    float* out = (float*)d_out;

    char* ws = (char*)d_ws;
    h16*   wfg = (h16*)ws;                                   // 65536 B
    short* kvt = (short*)(ws + 65536);                       // 4325376 B
    float* ksf = (float*)(ws + 65536 + 4325376);             // 65536 B

    int split = 8;
    while (split > 1) {
        size_t need = 65536ull + 4325376ull + 65536ull
                    + (size_t)split * (4194304ull + 65536ull);
        if (need <= ws_size) break;
        split >>= 1;
    }
    float* kvp = (float*)(ws + 65536 + 4325376 + 65536);
    float* ksp = kvp + (size_t)split * (256 * 64 * BH_);
    int nch = (T_ / split) / 128;

    k_prep  <<<dim3(64),           dim3(256), 0, stream>>>(W, wfg);
    k_stage1<<<dim3(split, BH_),   dim3(512), 0, stream>>>(k, v, m, wfg, kvp, ksp, nch);
    k_reduce<<<dim3(8, BH_),       dim3(256), 0, stream>>>(kvp, ksp, kvt, ksf, split);
    k_stage2<<<dim3(T_ / 128, BH_), dim3(512), 0, stream>>>(q, wfg, kvt, ksf, out);
}

// Round 10
// 249.686 us; speedup vs baseline: 3.6796x; 1.3062x over previous
//
#include <hip/hip_runtime.h>
#include <math.h>

#define T_     4096
#define BH_    64
#define EPS_   1e-6f
#define SCALE_ 0.0625f   // 1/sqrt(256)

typedef _Float16 h16;
typedef __attribute__((ext_vector_type(4))) _Float16 h16x4;
typedef __attribute__((ext_vector_type(8))) _Float16 h16x8;
typedef __attribute__((ext_vector_type(4))) short    short4v;
typedef __attribute__((ext_vector_type(8))) short    bf16x8;
typedef __attribute__((ext_vector_type(4))) float    f32x4;
typedef __attribute__((ext_vector_type(4))) unsigned uint4v;

__device__ __forceinline__ void bfsplit(float x, short& h, short& l) {
    unsigned u = __float_as_uint(x) + 0x8000u;       // round-half-up to bf16
    unsigned hb = u & 0xffff0000u;
    h = (short)(u >> 16);
    float lf = x - __uint_as_float(hb);              // exact residual
    l = (short)(__float_as_uint(lf) >> 16);          // truncated residual
}
// pack bf16(a) (low) | bf16(b) (high), round-half-up; returns residual bit patterns
__device__ __forceinline__ unsigned pk_hi2(float a, float b, unsigned& ra, unsigned& rb) {
    unsigned ua = __float_as_uint(a) + 0x8000u;
    unsigned ub = __float_as_uint(b) + 0x8000u;
    ra = ua & 0xffff0000u; rb = ub & 0xffff0000u;
    return __builtin_amdgcn_perm(ub, ua, 0x07060302u);
}
__device__ __forceinline__ unsigned pk_tr2(float a, float b) {   // truncating pack
    return __builtin_amdgcn_perm(__float_as_uint(b), __float_as_uint(a), 0x07060302u);
}
__device__ __forceinline__ bf16x8 mkbf8(unsigned a, unsigned b, unsigned c, unsigned d) {
    uint4v t; t.x = a; t.y = b; t.z = c; t.w = d;
    return __builtin_bit_cast(bf16x8, t);
}

// ============================================================
// prep: W (64x256) -> MFMA-fragment-ordered f16 hi/lo planes wfg:
//   frag(r, w, q)[8] = W^T[r][w*32+q*4 .. +3] ++ W^T[r][w*32+16+q*4 .. +3]
//   hi plane at [0, 16384) h16, lo plane at +16384. (HW-validated r7.)
// ============================================================
__global__ __launch_bounds__(256)
void k_prep(const float* __restrict__ Wg, h16* __restrict__ wfg)
{
    int d = blockIdx.x;      // 0..63
    int r = threadIdx.x;     // 0..255
    float x = Wg[d * 256 + r];
    h16 hi = (h16)x;
    h16 lo = (h16)(x - (float)hi);
    int w = d >> 5, rem = d & 31;
    int half = rem >> 4, qq = (rem >> 2) & 3, i = rem & 3;
    int dst = (r * 8 + w * 4 + qq) * 8 + half * 4 + i;
    wfg[dst]         = hi;
    wfg[16384 + dst] = lo;
}

// ============================================================
// Stage 1: 4-wave blocks (256 thr), 64-t chunks. Wave rg owns r-strip
// [rg*64, rg*64+64) fully: proj (f16x3) -> exp -> kv (bf16x3) accumulated
// over all t — NO cross-wave reduce. 2 indep blocks/CU (desync barriers).
// grid(split, BH).
// ============================================================
__global__ __launch_bounds__(256, 2)
void k_stage1(const float* __restrict__ kg, const float* __restrict__ vg,
              const float* __restrict__ mg, const h16* __restrict__ wfg,
              float* __restrict__ kv_part, float* __restrict__ ks_part, int nch)
{
    __shared__ __align__(16) char smem[19968];
    short* vTh    = (short*)smem;                   // [64 d][72] 9216 B
    short* vTl    = (short*)(smem + 9216);          // [64 d][72] 9216 B
    float* np     = (float*)(smem + 18432);         // [4][64]    1024 B
    float* norm_l = (float*)(smem + 19456);         // [64]        256 B
    float* msk_l  = (float*)(smem + 19712);         // [64]        256 B

    const int tid  = threadIdx.x;
    const int lane = tid & 63, l15 = lane & 15, q = lane >> 4;
    const int rg   = tid >> 6;                      // wave id = r-strip
    const int s = blockIdx.x, bh = blockIdx.y, b = bh >> 4;
    const long rowb = (long)bh * T_;

    f32x4 kva[4][4];
#pragma unroll
    for (int a = 0; a < 4; ++a)
#pragma unroll
        for (int c2 = 0; c2 < 4; ++c2) { f32x4 z4 = {0.f,0.f,0.f,0.f}; kva[a][c2] = z4; }
    float ksa[4] = {0.f, 0.f, 0.f, 0.f};

    const int tlv = tid & 63;      // staging: t row
    const int dq  = tid >> 6;      // staging: 16-d quarter

    for (int c = 0; c < nch; ++c) {
        const int t0 = (s * nch + c) * 64;
        __syncthreads();   // prev chunk's vT consumers done

        // ---- stage v^T (mask-scaled, bf16 hi/lo) + k row-norm partials ----
        {
            const float mval = mg[b * T_ + t0 + tlv];
            const float* vrow = vg + (rowb + t0 + tlv) * 64 + dq * 16;
            const float* krow = kg + (rowb + t0 + tlv) * 64 + dq * 16;
            float s2 = 0.f;
#pragma unroll
            for (int j = 0; j < 4; ++j) {
                float4 vv = *(const float4*)(vrow + j * 4);
                float4 kk = *(const float4*)(krow + j * 4);
                s2 += kk.x * kk.x + kk.y * kk.y + kk.z * kk.z + kk.w * kk.w;
                float xs[4] = {vv.x * mval, vv.y * mval, vv.z * mval, vv.w * mval};
#pragma unroll
                for (int e = 0; e < 4; ++e) {
                    int d = dq * 16 + j * 4 + e;
                    short hi, lo;
                    bfsplit(xs[e], hi, lo);
                    vTh[d * 72 + tlv] = hi;
                    vTl[d * 72 + tlv] = lo;
                }
            }
            np[dq * 64 + tlv] = s2;
        }
        __syncthreads();   // staging visible
        if (tid < 64) {    // norm pass (read in exp phase, after next barrier)
            norm_l[tid] = 0.5f * (np[tid] + np[64 + tid] + np[128 + tid] + np[192 + tid]);
            msk_l[tid]  = mg[b * T_ + t0 + tid] * SCALE_;
        }

        // ---- proj: pr[m][n]; rows t = t0+m*16+{l15|4q+j}, cols r = rg*64+n*16+l15 ----
        f32x4 pr[4][4];
#pragma unroll
        for (int m = 0; m < 4; ++m)
#pragma unroll
            for (int n = 0; n < 4; ++n) { f32x4 z4 = {0.f,0.f,0.f,0.f}; pr[m][n] = z4; }

#pragma unroll
        for (int w = 0; w < 2; ++w) {   // 32-d K windows
            h16x8 ah[4], al[4];
#pragma unroll
            for (int m = 0; m < 4; ++m) {
                const float* arow = kg + (rowb + t0 + m * 16 + l15) * 64 + w * 32 + q * 4;
                float4 x0 = *(const float4*)arow;
                float4 x1 = *(const float4*)(arow + 16);
                h16x8 hv, lv;
                hv[0] = (h16)x0.x; hv[1] = (h16)x0.y; hv[2] = (h16)x0.z; hv[3] = (h16)x0.w;
                hv[4] = (h16)x1.x; hv[5] = (h16)x1.y; hv[6] = (h16)x1.z; hv[7] = (h16)x1.w;
                lv[0] = (h16)(x0.x - (float)hv[0]); lv[1] = (h16)(x0.y - (float)hv[1]);
                lv[2] = (h16)(x0.z - (float)hv[2]); lv[3] = (h16)(x0.w - (float)hv[3]);
                lv[4] = (h16)(x1.x - (float)hv[4]); lv[5] = (h16)(x1.y - (float)hv[5]);
                lv[6] = (h16)(x1.z - (float)hv[6]); lv[7] = (h16)(x1.w - (float)hv[7]);
                ah[m] = hv; al[m] = lv;
            }
            h16x8 wbh[4], wbl[4];
#pragma unroll
            for (int n = 0; n < 4; ++n) {
                int fb = ((rg * 64 + n * 16 + l15) * 8 + w * 4 + q) * 8;
                wbh[n] = *(const h16x8*)&wfg[fb];
                wbl[n] = *(const h16x8*)&wfg[16384 + fb];
            }
#pragma unroll
            for (int m = 0; m < 4; ++m)
#pragma unroll
                for (int n = 0; n < 4; ++n) {
                    pr[m][n] = __builtin_amdgcn_mfma_f32_16x16x32_f16(ah[m], wbh[n], pr[m][n], 0, 0, 0);
                    pr[m][n] = __builtin_amdgcn_mfma_f32_16x16x32_f16(ah[m], wbl[n], pr[m][n], 0, 0, 0);
                    pr[m][n] = __builtin_amdgcn_mfma_f32_16x16x32_f16(al[m], wbh[n], pr[m][n], 0, 0, 0);
                }
        }
        __syncthreads();   // norm_l/msk_l visible to all waves

        // ---- per 32-t window: exp -> bf16 split A-frags -> kv MFMA ----
#pragma unroll
        for (int W = 0; W < 2; ++W) {
            const int m0 = 2 * W, m1 = 2 * W + 1;
            const int rb0 = m0 * 16 + q * 4;
            float4 nq0 = *(const float4*)&norm_l[rb0];
            float4 nq1 = *(const float4*)&norm_l[rb0 + 16];
            float4 sm0 = *(const float4*)&msk_l[rb0];
            float4 sm1 = *(const float4*)&msk_l[rb0 + 16];
            bf16x8 afh[4], afl[4];
#pragma unroll
            for (int n = 0; n < 4; ++n) {
                float ee[8];
                ee[0] = __expf(pr[m0][n][0] - nq0.x) * sm0.x;
                ee[1] = __expf(pr[m0][n][1] - nq0.y) * sm0.y;
                ee[2] = __expf(pr[m0][n][2] - nq0.z) * sm0.z;
                ee[3] = __expf(pr[m0][n][3] - nq0.w) * sm0.w;
                ee[4] = __expf(pr[m1][n][0] - nq1.x) * sm1.x;
                ee[5] = __expf(pr[m1][n][1] - nq1.y) * sm1.y;
                ee[6] = __expf(pr[m1][n][2] - nq1.z) * sm1.z;
                ee[7] = __expf(pr[m1][n][3] - nq1.w) * sm1.w;
                ksa[n] += ee[0]+ee[1]+ee[2]+ee[3]+ee[4]+ee[5]+ee[6]+ee[7];
                unsigned r0,r1,r2,r3,r4,r5,r6,r7;
                unsigned h01 = pk_hi2(ee[0], ee[1], r0, r1);
                unsigned h23 = pk_hi2(ee[2], ee[3], r2, r3);
                unsigned h45 = pk_hi2(ee[4], ee[5], r4, r5);
                unsigned h67 = pk_hi2(ee[6], ee[7], r6, r7);
                unsigned l01 = pk_tr2(ee[0]-__uint_as_float(r0), ee[1]-__uint_as_float(r1));
                unsigned l23 = pk_tr2(ee[2]-__uint_as_float(r2), ee[3]-__uint_as_float(r3));
                unsigned l45 = pk_tr2(ee[4]-__uint_as_float(r4), ee[5]-__uint_as_float(r5));
                unsigned l67 = pk_tr2(ee[6]-__uint_as_float(r6), ee[7]-__uint_as_float(r7));
                afh[n] = mkbf8(h01, h23, h45, h67);
                afl[n] = mkbf8(l01, l23, l45, l67);
            }
            bf16x8 bvh[4], bvl[4];
#pragma unroll
            for (int nd = 0; nd < 4; ++nd) {
                int base = (nd * 16 + l15) * 72 + W * 32 + q * 4;
                short4v a0 = *(const short4v*)&vTh[base];
                short4v a1 = *(const short4v*)&vTh[base + 16];
                short4v b0 = *(const short4v*)&vTl[base];
                short4v b1 = *(const short4v*)&vTl[base + 16];
                bf16x8 hv, lv;
                hv[0]=a0.x; hv[1]=a0.y; hv[2]=a0.z; hv[3]=a0.w; hv[4]=a1.x; hv[5]=a1.y; hv[6]=a1.z; hv[7]=a1.w;
                lv[0]=b0.x; lv[1]=b0.y; lv[2]=b0.z; lv[3]=b0.w; lv[4]=b1.x; lv[5]=b1.y; lv[6]=b1.z; lv[7]=b1.w;
                bvh[nd] = hv; bvl[nd] = lv;
            }
#pragma unroll
            for (int n = 0; n < 4; ++n)
#pragma unroll
                for (int nd = 0; nd < 4; ++nd) {
                    kva[n][nd] = __builtin_amdgcn_mfma_f32_16x16x32_bf16(afh[n], bvh[nd], kva[n][nd], 0, 0, 0);
                    kva[n][nd] = __builtin_amdgcn_mfma_f32_16x16x32_bf16(afh[n], bvl[nd], kva[n][nd], 0, 0, 0);
                    kva[n][nd] = __builtin_amdgcn_mfma_f32_16x16x32_bf16(afl[n], bvh[nd], kva[n][nd], 0, 0, 0);
                }
        }
    }

    // ---- block end: direct global writes (no cross-wave reduce) ----
#pragma unroll
    for (int n = 0; n < 4; ++n) {      // ksum: sum over q (t-quadrants)
        float v = ksa[n];
        v += __shfl_xor(v, 16);
        v += __shfl_xor(v, 32);
        if (q == 0) ks_part[(long)(s * BH_ + bh) * 256 + rg * 64 + n * 16 + l15] = v;
    }
    {
        const long pb = (long)(s * BH_ + bh) * (256 * 64);
#pragma unroll
        for (int n = 0; n < 4; ++n)
#pragma unroll
            for (int nd = 0; nd < 4; ++nd)
#pragma unroll
                for (int j = 0; j < 4; ++j)
                    kv_part[pb + (long)(rg * 64 + n * 16 + q * 4 + j) * 64 + nd * 16 + l15] = kva[n][nd][j];
    }
}

// ============================================================
// Reduce: sum split partials; emit kv^T bf16 hi/lo [bh][pl][64 d][264 r]
// + ksum_f.  grid(8, BH), 256 thr — each block: 32 r-rows of one head.
// ============================================================
__global__ __launch_bounds__(256)
void k_reduce(const float* __restrict__ kvp, const float* __restrict__ ksp,
              short* __restrict__ kvt, float* __restrict__ ksf, int split)
{
    __shared__ __align__(16) float red2[32 * 68];
    const int tid = threadIdx.x, rq = blockIdx.x, bh = blockIdx.y;
    const long NKV4 = (long)BH_ * 256 * 64 / 4;
#pragma unroll
    for (int i = 0; i < 2; ++i) {
        int idx4 = i * 256 + tid;
        long g = (long)bh * 4096 + rq * 512 + idx4;
        float4 a = ((const float4*)kvp)[g];
        for (int p = 1; p < split; ++p) {
            float4 t = ((const float4*)kvp)[(long)p * NKV4 + g];
            a.x += t.x; a.y += t.y; a.z += t.z; a.w += t.w;
        }
        int flat = idx4 * 4;
        int rl = flat >> 6, d = flat & 63;
        *(float4*)&red2[rl * 68 + d] = a;
    }
    if (tid < 32) {
        float s = 0.f;
        for (int p = 0; p < split; ++p) s += ksp[(long)p * (BH_ * 256) + bh * 256 + rq * 32 + tid];
        ksf[bh * 256 + rq * 32 + tid] = s;
    }
    __syncthreads();
    short* dh = kvt + (long)bh * 33792;
    short* dl = dh + 16896;
#pragma unroll
    for (int i = 0; i < 8; ++i) {
        int flat = i * 256 + tid;
        int d = flat >> 5, rl = flat & 31;
        short h, l;
        bfsplit(red2[rl * 68 + d], h, l);
        dh[d * 264 + rq * 32 + rl] = h;
        dl[d * 264 + rq * 32 + rl] = l;
    }
}

// ============================================================
// Stage 2: 4-wave blocks (256 thr), 64-t tiles. Wave rs owns r-strip;
// proj^T (f16x3) -> exp (+z) -> out (bf16x3) -> cross-rs reduce (red
// aliases dead kvT) -> divide. 2 indep blocks/CU. grid(64, BH).
// ============================================================
__global__ __launch_bounds__(256, 2)
void k_stage2(const float* __restrict__ qg, const h16* __restrict__ wfg,
              const short* __restrict__ kvt, const float* __restrict__ ksf,
              float* __restrict__ outg)
{
    __shared__ __align__(16) char smem[69632];
    short* kvTh   = (short*)smem;                   // [64*264] 33792 B
    short* kvTl   = (short*)(smem + 33792);         // [64*264] 33792 B
    float* ksum_l = (float*)(smem + 67584);         // [256]     1024 B
    float* zb     = (float*)(smem + 68608);         // [4][64]   1024 B
    float* red    = (float*)smem;                   // alias kvTh: 64*68*4 = 17408 B

    const int tid  = threadIdx.x;
    const int lane = tid & 63, l15 = lane & 15, q = lane >> 4;
    const int rs   = tid >> 6;                      // wave id = r-strip
    const int bh = blockIdx.y, t0 = blockIdx.x * 64;
    const long rowb = (long)bh * T_;

    {
        const float4* s2p = (const float4*)(kvt + (long)bh * 33792);
        float4* d2 = (float4*)kvTh;
#pragma unroll
        for (int i = 0; i < 17; ++i) { int idx = i * 256 + tid; if (idx < 4224) d2[idx] = s2p[idx]; }
        ksum_l[tid] = ksf[bh * 256 + tid];
    }
    __syncthreads();

    // ---- proj^T: rows r = rs*64+m*16+{l15|4q+j}, cols t = t0+n*16+l15 ----
    f32x4 pr[4][4];
#pragma unroll
    for (int m = 0; m < 4; ++m)
#pragma unroll
        for (int n = 0; n < 4; ++n) { f32x4 z4 = {0.f,0.f,0.f,0.f}; pr[m][n] = z4; }
    float nacc[4] = {0.f, 0.f, 0.f, 0.f};

#pragma unroll
    for (int w = 0; w < 2; ++w) {
        h16x8 aWh[4], aWl[4];
#pragma unroll
        for (int m = 0; m < 4; ++m) {
            int fb = ((rs * 64 + m * 16 + l15) * 8 + w * 4 + q) * 8;
            aWh[m] = *(const h16x8*)&wfg[fb];
            aWl[m] = *(const h16x8*)&wfg[16384 + fb];
        }
        h16x8 qbh[4], qbl[4];
#pragma unroll
        for (int n = 0; n < 4; ++n) {
            const float* qrow = qg + (rowb + t0 + n * 16 + l15) * 64 + w * 32 + q * 4;
            float4 x0 = *(const float4*)qrow;
            float4 x1 = *(const float4*)(qrow + 16);
            nacc[n] += x0.x * x0.x + x0.y * x0.y + x0.z * x0.z + x0.w * x0.w
                     + x1.x * x1.x + x1.y * x1.y + x1.z * x1.z + x1.w * x1.w;
            h16x8 hv, lv;
            hv[0] = (h16)x0.x; hv[1] = (h16)x0.y; hv[2] = (h16)x0.z; hv[3] = (h16)x0.w;
            hv[4] = (h16)x1.x; hv[5] = (h16)x1.y; hv[6] = (h16)x1.z; hv[7] = (h16)x1.w;
            lv[0] = (h16)(x0.x - (float)hv[0]); lv[1] = (h16)(x0.y - (float)hv[1]);
            lv[2] = (h16)(x0.z - (float)hv[2]); lv[3] = (h16)(x0.w - (float)hv[3]);
            lv[4] = (h16)(x1.x - (float)hv[4]); lv[5] = (h16)(x1.y - (float)hv[5]);
            lv[6] = (h16)(x1.z - (float)hv[6]); lv[7] = (h16)(x1.w - (float)hv[7]);
            qbh[n] = hv; qbl[n] = lv;
        }
#pragma unroll
        for (int m = 0; m < 4; ++m)
#pragma unroll
            for (int n = 0; n < 4; ++n) {
                pr[m][n] = __builtin_amdgcn_mfma_f32_16x16x32_f16(aWh[m], qbh[n], pr[m][n], 0, 0, 0);
                pr[m][n] = __builtin_amdgcn_mfma_f32_16x16x32_f16(aWh[m], qbl[n], pr[m][n], 0, 0, 0);
                pr[m][n] = __builtin_amdgcn_mfma_f32_16x16x32_f16(aWl[m], qbh[n], pr[m][n], 0, 0, 0);
            }
    }
    float normt[4];
#pragma unroll
    for (int n = 0; n < 4; ++n) {
        float v = nacc[n];
        v += __shfl_xor(v, 16);
        v += __shfl_xor(v, 32);
        normt[n] = 0.5f * v;
    }

    // ---- exp + z + out-GEMM per 32-r window ----
    f32x4 oac[4][4];
#pragma unroll
    for (int n = 0; n < 4; ++n)
#pragma unroll
        for (int nd = 0; nd < 4; ++nd) { f32x4 z4 = {0.f,0.f,0.f,0.f}; oac[n][nd] = z4; }
    float zp[4] = {0.f, 0.f, 0.f, 0.f};

#pragma unroll
    for (int W = 0; W < 2; ++W) {
        bf16x8 aph[4], apl[4];
#pragma unroll
        for (int n = 0; n < 4; ++n) {
            float ee[8];
#pragma unroll
            for (int half = 0; half < 2; ++half) {
                int m = 2 * W + half;
                int rl = rs * 64 + m * 16 + q * 4;
#pragma unroll
                for (int j = 0; j < 4; ++j) {
                    float e = __expf(pr[m][n][j] - normt[n]) * SCALE_;
                    zp[n] += e * ksum_l[rl + j];
                    ee[half * 4 + j] = e;
                }
            }
            unsigned r0,r1,r2,r3,r4,r5,r6,r7;
            unsigned h01 = pk_hi2(ee[0], ee[1], r0, r1);
            unsigned h23 = pk_hi2(ee[2], ee[3], r2, r3);
            unsigned h45 = pk_hi2(ee[4], ee[5], r4, r5);
            unsigned h67 = pk_hi2(ee[6], ee[7], r6, r7);
            unsigned l01 = pk_tr2(ee[0]-__uint_as_float(r0), ee[1]-__uint_as_float(r1));
            unsigned l23 = pk_tr2(ee[2]-__uint_as_float(r2), ee[3]-__uint_as_float(r3));
            unsigned l45 = pk_tr2(ee[4]-__uint_as_float(r4), ee[5]-__uint_as_float(r5));
            unsigned l67 = pk_tr2(ee[6]-__uint_as_float(r6), ee[7]-__uint_as_float(r7));
            aph[n] = mkbf8(h01, h23, h45, h67);
            apl[n] = mkbf8(l01, l23, l45, l67);
        }
        bf16x8 bkh[4], bkl[4];
#pragma unroll
        for (int nd = 0; nd < 4; ++nd) {
            int d  = nd * 16 + l15;
            int rb = rs * 64 + W * 32 + q * 4;
            short4v a0 = *(const short4v*)&kvTh[d * 264 + rb];
            short4v a1 = *(const short4v*)&kvTh[d * 264 + rb + 16];
            short4v b0 = *(const short4v*)&kvTl[d * 264 + rb];
            short4v b1 = *(const short4v*)&kvTl[d * 264 + rb + 16];
            bf16x8 hv, lv;
            hv[0]=a0.x; hv[1]=a0.y; hv[2]=a0.z; hv[3]=a0.w; hv[4]=a1.x; hv[5]=a1.y; hv[6]=a1.z; hv[7]=a1.w;
            lv[0]=b0.x; lv[1]=b0.y; lv[2]=b0.z; lv[3]=b0.w; lv[4]=b1.x; lv[5]=b1.y; lv[6]=b1.z; lv[7]=b1.w;
            bkh[nd] = hv; bkl[nd] = lv;
        }
#pragma unroll
        for (int n = 0; n < 4; ++n)
#pragma unroll
            for (int nd = 0; nd < 4; ++nd) {
                oac[n][nd] = __builtin_amdgcn_mfma_f32_16x16x32_bf16(aph[n], bkh[nd], oac[n][nd], 0, 0, 0);
                oac[n][nd] = __builtin_amdgcn_mfma_f32_16x16x32_bf16(aph[n], bkl[nd], oac[n][nd], 0, 0, 0);
                oac[n][nd] = __builtin_amdgcn_mfma_f32_16x16x32_bf16(apl[n], bkh[nd], oac[n][nd], 0, 0, 0);
            }
    }
#pragma unroll
    for (int n = 0; n < 4; ++n) {   // z partials (sum over r-quadrants)
        float v = zp[n];
        v += __shfl_xor(v, 16);
        v += __shfl_xor(v, 32);
        if (q == 0) zb[rs * 64 + n * 16 + l15] = v;
    }
    __syncthreads();   // all kvT reads done -> red (alias) writable; zb visible

    // ---- sequential reduce over r-strips into red ----
#pragma unroll
    for (int p = 0; p < 4; ++p) {
        if (rs == p) {
#pragma unroll
            for (int n = 0; n < 4; ++n)
#pragma unroll
                for (int nd = 0; nd < 4; ++nd)
#pragma unroll
                    for (int j = 0; j < 4; ++j) {
                        int idx = (n * 16 + q * 4 + j) * 68 + nd * 16 + l15;
                        if (p == 0) red[idx] = oac[n][nd][j];
                        else        red[idx] += oac[n][nd][j];
                    }
        }
        __syncthreads();
    }

    // ---- epilogue: divide by z+eps, store ----
#pragma unroll
    for (int i = 0; i < 4; ++i) {
        int flat = i * 1024 + tid * 4;
        int tl = flat >> 6, d = flat & 63;
        float z = zb[tl] + zb[64 + tl] + zb[128 + tl] + zb[192 + tl] + EPS_;
        float rz = 1.f / z;
        float4 o = *(const float4*)&red[tl * 68 + d];
        o.x *= rz; o.y *= rz; o.z *= rz; o.w *= rz;
        *(float4*)&outg[(rowb + t0 + tl) * 64 + d] = o;
    }
}

// ============================================================
extern "C" void kernel_launch(void* const* d_in, const int* in_sizes, int n_in,
                              void* d_out, int out_size, void* d_ws, size_t ws_size,
                              hipStream_t stream)
{
    const float* q  = (const float*)d_in[0];
    const float* k  = (const float*)d_in[1];
    const float* v  = (const float*)d_in[2];
    const float* m  = (const float*)d_in[3];
    const float* W  = (const float*)d_in[4];
    float* out = (float*)d_out;

    char* ws = (char*)d_ws;
    h16*   wfg = (h16*)ws;                                   // 65536 B
    short* kvt = (short*)(ws + 65536);                       // 4325376 B
    float* ksf = (float*)(ws + 65536 + 4325376);             // 65536 B

    int split = 8;
    while (split > 1) {
        size_t need = 65536ull + 4325376ull + 65536ull
                    + (size_t)split * (4194304ull + 65536ull);
        if (need <= ws_size) break;
        split >>= 1;
    }
    float* kvp = (float*)(ws + 65536 + 4325376 + 65536);
    float* ksp = kvp + (size_t)split * (256 * 64 * BH_);
    int nch = (T_ / split) / 64;

    k_prep  <<<dim3(64),           dim3(256), 0, stream>>>(W, wfg);
    k_stage1<<<dim3(split, BH_),   dim3(256), 0, stream>>>(k, v, m, wfg, kvp, ksp, nch);
    k_reduce<<<dim3(8, BH_),       dim3(256), 0, stream>>>(kvp, ksp, kvt, ksf, split);
    k_stage2<<<dim3(T_ / 64, BH_), dim3(256), 0, stream>>>(q, wfg, kvt, ksf, out);
}